// Round 10
// baseline (1042.176 us; speedup 1.0000x reference)
//
#include <hip/hip_runtime.h>
#include <hip/hip_bf16.h>

#define MSAMP 4096
#define D0    512
#define EXPN  8192
#define NCLS  1000
#define NPAD  1024
#define QSCALE     (6.0f / 127.0f)
#define QSCALE_INV (127.0f / 6.0f)

typedef __attribute__((ext_vector_type(8))) _Float16       half8;
typedef __attribute__((ext_vector_type(8))) unsigned short ushort8v;
typedef __attribute__((ext_vector_type(4))) float          f32x4;
typedef __attribute__((ext_vector_type(4))) int            i32x4v;

__device__ __forceinline__ unsigned short f2h(float f) {
    union { _Float16 h; unsigned short u; } c; c.h = (_Float16)f; return c.u;
}
__device__ __forceinline__ float h2f(unsigned short u) {
    union { unsigned short u; _Float16 h; } c; c.u = u; return (float)c.h;
}
__device__ __forceinline__ ushort8v relu8h(ushort8v v) {   // f16 relu: sign bit
#pragma unroll
    for (int j = 0; j < 8; ++j) v[j] = (v[j] & 0x8000u) ? (unsigned short)0 : v[j];
    return v;
}
__device__ __forceinline__ half8 as_half8(const unsigned short* p) {
    return *(const half8*)p;
}
__device__ __forceinline__ float tanh_fast(float x) {
    float e = __expf(2.0f * x);
    return 1.0f - 2.0f * __builtin_amdgcn_rcpf(e + 1.0f);
}
// Bank swizzle (verified R9: conflicts 1.73e7 -> 0): fold bit5 of the 16B-unit
// row index into bit2. Writes fold 4*(tid&1) into l_w; reads fold 4*(lane>=32)
// into lane. Same bijection both sides -> bit-exact.

// ---------------------------------------------------------------------------
// X f32 [4096][512] -> f16
// ---------------------------------------------------------------------------
__global__ __launch_bounds__(256) void cvt_x(const float* __restrict__ src,
                                             unsigned short* __restrict__ dst)
{
    const size_t i = ((size_t)blockIdx.x * 256 + threadIdx.x) * 8;
    float4 v0 = *(const float4*)(src + i), v1 = *(const float4*)(src + i + 4);
    union { unsigned short u[8]; ushort8v v; } H;
    H.u[0] = f2h(v0.x); H.u[1] = f2h(v0.y); H.u[2] = f2h(v0.z); H.u[3] = f2h(v0.w);
    H.u[4] = f2h(v1.x); H.u[5] = f2h(v1.y); H.u[6] = f2h(v1.z); H.u[7] = f2h(v1.w);
    *(ushort8v*)(dst + i) = H.v;
}

// ---------------------------------------------------------------------------
// Wb [512][8192] f32 -> WbT f16 [8192][512]
// ---------------------------------------------------------------------------
__global__ void transpose_wb(const float* __restrict__ src,
                             unsigned short* __restrict__ dst)
{
    __shared__ float t[32][33];
    const int n0 = blockIdx.x * 32, k0 = blockIdx.y * 32;
    const int tx = threadIdx.x, ty = threadIdx.y;
#pragma unroll
    for (int i = 0; i < 4; ++i)
        t[ty + 8 * i][tx] = src[(size_t)(k0 + ty + 8 * i) * EXPN + n0 + tx];
    __syncthreads();
#pragma unroll
    for (int i = 0; i < 4; ++i)
        dst[(size_t)(n0 + ty + 8 * i) * D0 + k0 + tx] = f2h(t[tx][ty + 8 * i]);
}

// ---------------------------------------------------------------------------
// Xe(f16) = X @ Wb via f16 MFMA, NT, K=512. Fragment-major LDS, K-step 64,
// bank-swizzled rows (l_ws/lane_s).
// ---------------------------------------------------------------------------
__global__ __launch_bounds__(256) void gemm_xe_mfma(
    const unsigned short* __restrict__ Xh, const unsigned short* __restrict__ WbT,
    unsigned short* __restrict__ Xe)
{
    __shared__ __align__(16) char smem[34816];
    unsigned short (*AsF)[2][64][8] = (unsigned short (*)[2][64][8])(smem);
    unsigned short (*BsF)[2][64][8] = (unsigned short (*)[2][64][8])(smem + 16384);

    const int tid = threadIdx.x;
    const int wid = tid >> 6, lane = tid & 63;
    const int l15 = lane & 15, q = lane >> 4;
    const int wm = (wid >> 1) * 64, wn = (wid & 1) * 64;
    const int row0 = blockIdx.y * 128, col0 = blockIdx.x * 128;

    const int sr = tid >> 1;
    const int scp = (tid & 1) * 2;
    const int mi_w = sr >> 4;
    const int l_ws = (sr & 15) ^ ((tid & 1) << 2);     // bank-swizzled write row
    const int lane_s = lane ^ ((lane >> 3) & 4);       // bank-swizzled read row

    f32x4 acc[4][4];
#pragma unroll
    for (int m = 0; m < 4; ++m)
#pragma unroll
        for (int n = 0; n < 4; ++n) acc[m][n] = (f32x4){0.f, 0.f, 0.f, 0.f};

    for (int k0 = 0; k0 < D0; k0 += 64) {
        const unsigned short* pa = Xh  + (size_t)(row0 + sr) * D0 + k0 + scp * 8;
        const unsigned short* pb = WbT + (size_t)(col0 + sr) * D0 + k0 + scp * 8;
        ushort8v a0 = *(const ushort8v*)pa,        a1 = *(const ushort8v*)(pa + 8);
        ushort8v a2 = *(const ushort8v*)(pa + 32), a3 = *(const ushort8v*)(pa + 40);
        ushort8v b0 = *(const ushort8v*)pb,        b1 = *(const ushort8v*)(pb + 8);
        ushort8v b2 = *(const ushort8v*)(pb + 32), b3 = *(const ushort8v*)(pb + 40);

        __syncthreads();
        *(ushort8v*)&AsF[mi_w][0][scp * 16 + l_ws][0]       = a0;
        *(ushort8v*)&AsF[mi_w][0][(scp + 1) * 16 + l_ws][0] = a1;
        *(ushort8v*)&AsF[mi_w][1][scp * 16 + l_ws][0]       = a2;
        *(ushort8v*)&AsF[mi_w][1][(scp + 1) * 16 + l_ws][0] = a3;
        *(ushort8v*)&BsF[mi_w][0][scp * 16 + l_ws][0]       = b0;
        *(ushort8v*)&BsF[mi_w][0][(scp + 1) * 16 + l_ws][0] = b1;
        *(ushort8v*)&BsF[mi_w][1][scp * 16 + l_ws][0]       = b2;
        *(ushort8v*)&BsF[mi_w][1][(scp + 1) * 16 + l_ws][0] = b3;
        __syncthreads();

        half8 fa[4][2], fb[4][2];
#pragma unroll
        for (int m = 0; m < 4; ++m) {
            fa[m][0] = as_half8(&AsF[(wm >> 4) + m][0][lane_s][0]);
            fa[m][1] = as_half8(&AsF[(wm >> 4) + m][1][lane_s][0]);
            fb[m][0] = as_half8(&BsF[(wn >> 4) + m][0][lane_s][0]);
            fb[m][1] = as_half8(&BsF[(wn >> 4) + m][1][lane_s][0]);
        }
#pragma unroll
        for (int m = 0; m < 4; ++m)
#pragma unroll
            for (int n = 0; n < 4; ++n) {
                acc[m][n] = __builtin_amdgcn_mfma_f32_16x16x32_f16(fa[m][0], fb[n][0], acc[m][n], 0, 0, 0);
                acc[m][n] = __builtin_amdgcn_mfma_f32_16x16x32_f16(fa[m][1], fb[n][1], acc[m][n], 0, 0, 0);
            }
    }

    unsigned short (*Cb)[136] = (unsigned short (*)[136])smem;
    const int rr = tid >> 1, hh = (tid & 1) * 64;
    __syncthreads();
#pragma unroll
    for (int m = 0; m < 4; ++m)
#pragma unroll
        for (int n = 0; n < 4; ++n)
#pragma unroll
            for (int r = 0; r < 4; ++r)
                Cb[wm + m * 16 + q * 4 + r][wn + n * 16 + l15] = f2h(acc[m][n][r]);
    __syncthreads();
#pragma unroll
    for (int c = 0; c < 8; ++c)
        *(ushort8v*)&Xe[(size_t)(row0 + rr) * EXPN + col0 + hh + c * 8] =
            *(const ushort8v*)&Cb[rr][hh + c * 8];
}

// ---------------------------------------------------------------------------
// sim partials, split-K=2. Grid (528, 2): t = tile-pair, kh = K-half.
//   kh=0: raw f32 partial -> final Sm slot [gi][gj] (upper-tri, uniquely owned)
//   kh=1: raw f32 partial -> P1[t] tile-contiguous (SEG1 scratch)
// Inner loop identical to R9 (K-step 64, bank-swizzled LDS). sim_combine
// adds, scales by invn, sets diag, mirrors.
// ---------------------------------------------------------------------------
__global__ __launch_bounds__(256) void gemm_sim(
    const unsigned short* __restrict__ Xe, float* __restrict__ Sm,
    float* __restrict__ P1)
{
    __shared__ unsigned short AsF[8][2][64][8], BsF[8][2][64][8];   // 32 KiB

    const int t = blockIdx.x;
    const int kh = blockIdx.y;
    int bj = (int)((sqrtf(8.0f * t + 1.0f) - 1.0f) * 0.5f);
    while ((bj + 1) * (bj + 2) / 2 <= t) ++bj;
    while (bj * (bj + 1) / 2 > t) --bj;
    const int bi = t - bj * (bj + 1) / 2;
    const int row0 = bi * 128, col0 = bj * 128;
    const int kbase = kh * (EXPN / 2);

    const int tid = threadIdx.x;
    const int wid = tid >> 6, lane = tid & 63;
    const int l15 = lane & 15, q = lane >> 4;
    const int wm = (wid >> 1) * 64, wn = (wid & 1) * 64;

    const int sr = tid >> 1;
    const int scp = (tid & 1) * 2;
    const int mi_w = sr >> 4;
    const int l_ws = (sr & 15) ^ ((tid & 1) << 2);
    const int lane_s = lane ^ ((lane >> 3) & 4);

    f32x4 acc[4][4];
#pragma unroll
    for (int m = 0; m < 4; ++m)
#pragma unroll
        for (int n = 0; n < 4; ++n) acc[m][n] = (f32x4){0.f, 0.f, 0.f, 0.f};

    for (int kk = 0; kk < EXPN / 2; kk += 64) {
        const int k0 = kbase + kk;
        const unsigned short* pa = Xe + (size_t)(row0 + sr) * EXPN + k0 + scp * 8;
        const unsigned short* pb = Xe + (size_t)(col0 + sr) * EXPN + k0 + scp * 8;
        ushort8v a0 = *(const ushort8v*)pa,        a1 = *(const ushort8v*)(pa + 8);
        ushort8v a2 = *(const ushort8v*)(pa + 32), a3 = *(const ushort8v*)(pa + 40);
        ushort8v b0 = *(const ushort8v*)pb,        b1 = *(const ushort8v*)(pb + 8);
        ushort8v b2 = *(const ushort8v*)(pb + 32), b3 = *(const ushort8v*)(pb + 40);

        __syncthreads();
        *(ushort8v*)&AsF[mi_w][0][scp * 16 + l_ws][0]       = a0;
        *(ushort8v*)&AsF[mi_w][0][(scp + 1) * 16 + l_ws][0] = a1;
        *(ushort8v*)&AsF[mi_w][1][scp * 16 + l_ws][0]       = a2;
        *(ushort8v*)&AsF[mi_w][1][(scp + 1) * 16 + l_ws][0] = a3;
        *(ushort8v*)&BsF[mi_w][0][scp * 16 + l_ws][0]       = b0;
        *(ushort8v*)&BsF[mi_w][0][(scp + 1) * 16 + l_ws][0] = b1;
        *(ushort8v*)&BsF[mi_w][1][scp * 16 + l_ws][0]       = b2;
        *(ushort8v*)&BsF[mi_w][1][(scp + 1) * 16 + l_ws][0] = b3;
        __syncthreads();

        half8 fa[4][2], fb[4][2];
#pragma unroll
        for (int m = 0; m < 4; ++m) {
            fa[m][0] = as_half8(&AsF[(wm >> 4) + m][0][lane_s][0]);
            fa[m][1] = as_half8(&AsF[(wm >> 4) + m][1][lane_s][0]);
            fb[m][0] = as_half8(&BsF[(wn >> 4) + m][0][lane_s][0]);
            fb[m][1] = as_half8(&BsF[(wn >> 4) + m][1][lane_s][0]);
        }
#pragma unroll
        for (int m = 0; m < 4; ++m)
#pragma unroll
            for (int n = 0; n < 4; ++n) {
                acc[m][n] = __builtin_amdgcn_mfma_f32_16x16x32_f16(fa[m][0], fb[n][0], acc[m][n], 0, 0, 0);
                acc[m][n] = __builtin_amdgcn_mfma_f32_16x16x32_f16(fa[m][1], fb[n][1], acc[m][n], 0, 0, 0);
            }
    }

    if (kh == 0) {
#pragma unroll
        for (int m = 0; m < 4; ++m)
#pragma unroll
            for (int n = 0; n < 4; ++n) {
                const int gj = col0 + wn + n * 16 + l15;
#pragma unroll
                for (int r = 0; r < 4; ++r) {
                    const int gi = row0 + wm + m * 16 + q * 4 + r;
                    Sm[(size_t)gi * MSAMP + gj] = acc[m][n][r];
                }
            }
    } else {
        float* dp = P1 + (size_t)t * 16384;
#pragma unroll
        for (int m = 0; m < 4; ++m)
#pragma unroll
            for (int n = 0; n < 4; ++n) {
                const int lj = wn + n * 16 + l15;
#pragma unroll
                for (int r = 0; r < 4; ++r) {
                    const int li = wm + m * 16 + q * 4 + r;
                    dp[li * 128 + lj] = acc[m][n][r];
                }
            }
    }
}

// ---------------------------------------------------------------------------
// Sm[tile t] = (Sm_partial0 + P1[t]) * invn_i * invn_j, diag=-3e38, + mirror.
// In-place on own tile; mirror targets lower-tri (uniquely owned by t).
// ---------------------------------------------------------------------------
__global__ __launch_bounds__(256) void sim_combine(
    float* __restrict__ Sm, const float* __restrict__ P1,
    const float* __restrict__ invn)
{
    const int t = blockIdx.x;
    int bj = (int)((sqrtf(8.0f * t + 1.0f) - 1.0f) * 0.5f);
    while ((bj + 1) * (bj + 2) / 2 <= t) ++bj;
    while (bj * (bj + 1) / 2 > t) --bj;
    const int bi = t - bj * (bj + 1) / 2;
    const int row0 = bi * 128, col0 = bj * 128;

    const int r  = threadIdx.x >> 1;
    const int c0 = (threadIdx.x & 1) * 64;
    const int gi = row0 + r;
    const float invi = invn[gi];
    const bool mirror = (bi != bj);

    float* srow = Sm + (size_t)gi * MSAMP + col0 + c0;
    const float* prow = P1 + (size_t)t * 16384 + r * 128 + c0;

#pragma unroll
    for (int i = 0; i < 16; ++i) {
        float4 a  = *(const float4*)(srow + i * 4);
        float4 b  = *(const float4*)(prow + i * 4);
        float4 nj = *(const float4*)(invn + col0 + c0 + i * 4);
        float v0 = (a.x + b.x) * invi * nj.x;
        float v1 = (a.y + b.y) * invi * nj.y;
        float v2 = (a.z + b.z) * invi * nj.z;
        float v3 = (a.w + b.w) * invi * nj.w;
        const int gj0 = col0 + c0 + i * 4;
        if (gi == gj0 + 0) v0 = -3.0e38f;
        if (gi == gj0 + 1) v1 = -3.0e38f;
        if (gi == gj0 + 2) v2 = -3.0e38f;
        if (gi == gj0 + 3) v3 = -3.0e38f;
        *(float4*)(srow + i * 4) = make_float4(v0, v1, v2, v3);
        if (mirror) {
            Sm[(size_t)(gj0 + 0) * MSAMP + gi] = v0;
            Sm[(size_t)(gj0 + 1) * MSAMP + gi] = v1;
            Sm[(size_t)(gj0 + 2) * MSAMP + gi] = v2;
            Sm[(size_t)(gj0 + 3) * MSAMP + gi] = v3;
        }
    }
}

// ---------------------------------------------------------------------------
// Tk(f16) = tanh((1/k) * Adj @ Xe) via i8 MFMA. K-step 128 (2 x 64),
// bank-swizzled fragment LDS. XCD chunked swizzle (2048 = 8*256).
// ---------------------------------------------------------------------------
__global__ __launch_bounds__(256) void gemm_adj_i8(
    const unsigned* __restrict__ Abits, const signed char* __restrict__ XeT,
    unsigned short* __restrict__ Tk, const int* __restrict__ kp)
{
    __shared__ signed char BsF[8][2][64][16];    // 32 KiB
    __shared__ uint4 aw4[128];

    const int tid = threadIdx.x;
    const int wid = tid >> 6, lane = tid & 63;
    const int l15 = lane & 15, q = lane >> 4;
    const int wm = (wid >> 1) * 64, wn = (wid & 1) * 64;

    const int orig = blockIdx.x + blockIdx.y * 32;   // grid (32, 64), 2048 blocks
    const int s = (orig & 7) * 256 + (orig >> 3);    // bijective XCD chunking
    const int row0 = (s & 31) * 128;                 // sample rows
    const int col0 = (s >> 5) * 128;                 // expansion cols

    const int sr = tid >> 1;
    const int half = tid & 1;
    const int l_ws = (sr & 15) ^ (half << 2);
    const int lane_s = lane ^ ((lane >> 3) & 4);

    i32x4v acc[4][4];
#pragma unroll
    for (int m = 0; m < 4; ++m)
#pragma unroll
        for (int n = 0; n < 4; ++n) acc[m][n] = (i32x4v){0, 0, 0, 0};

    for (int k0 = 0; k0 < MSAMP; k0 += 128) {
        const signed char* pb = XeT + (size_t)(col0 + sr) * MSAMP + k0 + half * 32;
        i32x4v b0 = *(const i32x4v*)pb;
        i32x4v b1 = *(const i32x4v*)(pb + 16);
        i32x4v b2 = *(const i32x4v*)(pb + 64);
        i32x4v b3 = *(const i32x4v*)(pb + 80);
        uint4 wv = make_uint4(0u, 0u, 0u, 0u);
        if (tid < 128)
            wv = *(const uint4*)(Abits + (size_t)(row0 + tid) * (MSAMP / 32) + (k0 >> 5));

        __syncthreads();
        *(i32x4v*)&BsF[sr >> 4][0][(half * 2 + 0) * 16 + l_ws][0] = b0;
        *(i32x4v*)&BsF[sr >> 4][0][(half * 2 + 1) * 16 + l_ws][0] = b1;
        *(i32x4v*)&BsF[sr >> 4][1][(half * 2 + 0) * 16 + l_ws][0] = b2;
        *(i32x4v*)&BsF[sr >> 4][1][(half * 2 + 1) * 16 + l_ws][0] = b3;
        if (tid < 128) aw4[tid] = wv;
        __syncthreads();

        i32x4v fb[4][2];
#pragma unroll
        for (int n = 0; n < 4; ++n) {
            fb[n][0] = *(const i32x4v*)&BsF[(wn >> 4) + n][0][lane_s][0];
            fb[n][1] = *(const i32x4v*)&BsF[(wn >> 4) + n][1][lane_s][0];
        }

#pragma unroll
        for (int m = 0; m < 4; ++m) {
            const uint4 ww = aw4[wm + m * 16 + l15];
#pragma unroll
            for (int kh = 0; kh < 2; ++kh) {
                const unsigned w = (kh == 0) ? ((q >= 2) ? ww.y : ww.x)
                                             : ((q >= 2) ? ww.w : ww.z);
                const unsigned hw = (q & 1) ? (w >> 16) : w;
                i32x4v fa;
#pragma unroll
                for (int p = 0; p < 4; ++p)
                    fa[p] = (int)((((hw >> (4 * p)) & 0xFu) * 0x00204081u) & 0x01010101u);
#pragma unroll
                for (int n = 0; n < 4; ++n)
                    acc[m][n] = __builtin_amdgcn_mfma_i32_16x16x64_i8(fa, fb[n][kh], acc[m][n], 0, 0, 0);
            }
        }
    }

    const float kv = QSCALE / (float)(*kp);
#pragma unroll
    for (int m = 0; m < 4; ++m)
#pragma unroll
        for (int n = 0; n < 4; ++n) {
            const int gj = col0 + wn + n * 16 + l15;
#pragma unroll
            for (int r = 0; r < 4; ++r) {
                const int gi = row0 + wm + m * 16 + q * 4 + r;
                Tk[(size_t)gi * EXPN + gj] = f2h(tanh_fast((float)acc[m][n][r] * kv));
            }
        }
}

// ---------------------------------------------------------------------------
// W [8192][1000] f32 -> WT f16 [NPAD][8192], zero-padded rows.
// ---------------------------------------------------------------------------
__global__ void transpose_w(const float* __restrict__ src,
                            unsigned short* __restrict__ dst)
{
    __shared__ float t[32][33];
    const int k0 = blockIdx.x * 32, n0 = blockIdx.y * 32;
    const int tx = threadIdx.x, ty = threadIdx.y;
#pragma unroll
    for (int i = 0; i < 4; ++i) {
        const int n = n0 + tx;
        t[ty + 8 * i][tx] = (n < NCLS) ? src[(size_t)(k0 + ty + 8 * i) * NCLS + n] : 0.f;
    }
    __syncthreads();
#pragma unroll
    for (int i = 0; i < 4; ++i)
        dst[(size_t)(n0 + ty + 8 * i) * EXPN + k0 + tx] = f2h(t[tx][ty + 8 * i]);
}

// ---------------------------------------------------------------------------
// Split-K=4, NO atomics. XCD chunked swizzle on (x,y), z preserved.
// K-step 64 (2 x 32), bank-swizzled fragment LDS, relu at ds_write time (z<2).
// ---------------------------------------------------------------------------
__global__ __launch_bounds__(256) void gemm_out_split(
    const unsigned short* __restrict__ Xe, const unsigned short* __restrict__ Tk,
    const unsigned short* __restrict__ WmT, const unsigned short* __restrict__ WcT,
    float* __restrict__ Cout, unsigned short* __restrict__ Pf)
{
    __shared__ unsigned short AsF[8][2][64][8], BsF[8][2][64][8];   // 32 KiB

    const int tid = threadIdx.x;
    const int wid = tid >> 6, lane = tid & 63;
    const int l15 = lane & 15, q = lane >> 4;
    const int wm = (wid >> 1) * 64, wn = (wid & 1) * 64;

    const int orig = blockIdx.x + blockIdx.y * 8;    // 256 blocks per z
    const int s = (orig & 7) * 32 + (orig >> 3);     // bijective XCD chunking
    const int col0 = (s & 7) * 128;
    const int row0 = (s >> 3) * 128;
    const int zz = blockIdx.z;
    const bool xe_side = (zz < 2);
    const int kbase = (zz & 1) * (EXPN / 2);

    const unsigned short* Abase = xe_side ? Xe : Tk;
    const unsigned short* Bbase = xe_side ? WmT : WcT;

    const int sr = tid >> 1;
    const int scp = (tid & 1) * 2;
    const int mi_w = sr >> 4;
    const int l_ws = (sr & 15) ^ ((tid & 1) << 2);
    const int lane_s = lane ^ ((lane >> 3) & 4);

    f32x4 acc[4][4];
#pragma unroll
    for (int m = 0; m < 4; ++m)
#pragma unroll
        for (int n = 0; n < 4; ++n) acc[m][n] = (f32x4){0.f, 0.f, 0.f, 0.f};

    for (int kk = 0; kk < EXPN / 2; kk += 64) {
        const int k0 = kbase + kk;
        const unsigned short* pa = Abase + (size_t)(row0 + sr) * EXPN + k0 + scp * 8;
        const unsigned short* pb = Bbase + (size_t)(col0 + sr) * EXPN + k0 + scp * 8;
        ushort8v a0 = *(const ushort8v*)pa,        a1 = *(const ushort8v*)(pa + 8);
        ushort8v a2 = *(const ushort8v*)(pa + 32), a3 = *(const ushort8v*)(pa + 40);
        ushort8v b0 = *(const ushort8v*)pb,        b1 = *(const ushort8v*)(pb + 8);
        ushort8v b2 = *(const ushort8v*)(pb + 32), b3 = *(const ushort8v*)(pb + 40);
        if (xe_side) { a0 = relu8h(a0); a1 = relu8h(a1); a2 = relu8h(a2); a3 = relu8h(a3); }

        __syncthreads();
        *(ushort8v*)&AsF[mi_w][0][scp * 16 + l_ws][0]       = a0;
        *(ushort8v*)&AsF[mi_w][0][(scp + 1) * 16 + l_ws][0] = a1;
        *(ushort8v*)&AsF[mi_w][1][scp * 16 + l_ws][0]       = a2;
        *(ushort8v*)&AsF[mi_w][1][(scp + 1) * 16 + l_ws][0] = a3;
        *(ushort8v*)&BsF[mi_w][0][scp * 16 + l_ws][0]       = b0;
        *(ushort8v*)&BsF[mi_w][0][(scp + 1) * 16 + l_ws][0] = b1;
        *(ushort8v*)&BsF[mi_w][1][scp * 16 + l_ws][0]       = b2;
        *(ushort8v*)&BsF[mi_w][1][(scp + 1) * 16 + l_ws][0] = b3;
        __syncthreads();

        half8 fa[4][2], fb[4][2];
#pragma unroll
        for (int m = 0; m < 4; ++m) {
            fa[m][0] = as_half8(&AsF[(wm >> 4) + m][0][lane_s][0]);
            fa[m][1] = as_half8(&AsF[(wm >> 4) + m][1][lane_s][0]);
            fb[m][0] = as_half8(&BsF[(wn >> 4) + m][0][lane_s][0]);
            fb[m][1] = as_half8(&BsF[(wn >> 4) + m][1][lane_s][0]);
        }
#pragma unroll
        for (int m = 0; m < 4; ++m)
#pragma unroll
            for (int n = 0; n < 4; ++n) {
                acc[m][n] = __builtin_amdgcn_mfma_f32_16x16x32_f16(fa[m][0], fb[n][0], acc[m][n], 0, 0, 0);
                acc[m][n] = __builtin_amdgcn_mfma_f32_16x16x32_f16(fa[m][1], fb[n][1], acc[m][n], 0, 0, 0);
            }
    }

    if (zz == 0) {
#pragma unroll
        for (int m = 0; m < 4; ++m)
#pragma unroll
            for (int n = 0; n < 4; ++n) {
                const int gj = col0 + wn + n * 16 + l15;
                if (gj < NCLS) {
#pragma unroll
                    for (int r = 0; r < 4; ++r) {
                        const int gi = row0 + wm + m * 16 + q * 4 + r;
                        Cout[(size_t)gi * NCLS + gj] = acc[m][n][r];
                    }
                }
            }
    } else {
        unsigned short* dp = Pf + (size_t)(zz - 1) * MSAMP * NCLS;
#pragma unroll
        for (int m = 0; m < 4; ++m)
#pragma unroll
            for (int n = 0; n < 4; ++n) {
                const int gj = col0 + wn + n * 16 + l15;
                if (gj < NCLS) {
#pragma unroll
                    for (int r = 0; r < 4; ++r) {
                        const int gi = row0 + wm + m * 16 + q * 4 + r;
                        dp[(size_t)gi * NCLS + gj] = f2h(acc[m][n][r]);
                    }
                }
            }
    }
}

// ---------------------------------------------------------------------------
// out[i] += P0[i] + P1[i] + P2[i]   (f16 partials -> f32 accumulate)
// ---------------------------------------------------------------------------
__global__ __launch_bounds__(256) void add_partials(float* __restrict__ out,
                                                    const unsigned short* __restrict__ P,
                                                    int n4)
{
    const int i = blockIdx.x * 256 + threadIdx.x;
    if (i < n4) {
        float4 a = ((const float4*)out)[i];
        const ushort4 p0 = *(const ushort4*)(P + (size_t)i * 4);
        const ushort4 p1 = *(const ushort4*)(P + (size_t)MSAMP * NCLS + (size_t)i * 4);
        const ushort4 p2 = *(const ushort4*)(P + (size_t)2 * MSAMP * NCLS + (size_t)i * 4);
        a.x += h2f(p0.x) + h2f(p1.x) + h2f(p2.x);
        a.y += h2f(p0.y) + h2f(p1.y) + h2f(p2.y);
        a.z += h2f(p0.z) + h2f(p1.z) + h2f(p2.z);
        a.w += h2f(p0.w) + h2f(p1.w) + h2f(p2.w);
        ((float4*)out)[i] = a;
    }
}

// ---------------------------------------------------------------------------
__global__ __launch_bounds__(256) void row_invnorm(
    const unsigned short* __restrict__ Xe, float* __restrict__ invn)
{
    const int row = blockIdx.x;
    float s = 0.f;
    for (int j = threadIdx.x * 8; j < EXPN; j += 2048) {
        ushort8v h = *(const ushort8v*)(Xe + (size_t)row * EXPN + j);
#pragma unroll
        for (int c = 0; c < 8; ++c) { float x = h2f(h[c]); s += x * x; }
    }
#pragma unroll
    for (int off = 32; off > 0; off >>= 1) s += __shfl_down(s, off);
    __shared__ float wsum[4];
    if ((threadIdx.x & 63) == 0) wsum[threadIdx.x >> 6] = s;
    __syncthreads();
    if (threadIdx.x == 0)
        invn[row] = rsqrtf(wsum[0] + wsum[1] + wsum[2] + wsum[3]);
}

// ---------------------------------------------------------------------------
__global__ __launch_bounds__(256) void topk_thresh(const float* __restrict__ sim,
                                                   float* __restrict__ thr,
                                                   int N, const int* __restrict__ kp)
{
    const int row = blockIdx.x;
    const float* srow = sim + (size_t)row * N;
    __shared__ int hist[256];
    __shared__ unsigned s_prefix;
    __shared__ int s_rem;
    if (threadIdx.x == 0) { s_prefix = 0u; s_rem = *kp; }
    __syncthreads();

    for (int pass = 0; pass < 4; ++pass) {
        const int shift = 24 - 8 * pass;
        hist[threadIdx.x] = 0;
        __syncthreads();
        const unsigned prefix = s_prefix;
        const unsigned pmask = (pass == 0) ? 0u : (0xFFFFFFFFu << (shift + 8));
        for (int j = threadIdx.x; j < N; j += 256) {
            unsigned u = __float_as_uint(srow[j]);
            u = ((int)u < 0) ? ~u : (u | 0x80000000u);
            if ((u & pmask) == (prefix & pmask))
                atomicAdd(&hist[(u >> shift) & 255], 1);
        }
        __syncthreads();
        if (threadIdx.x == 0) {
            int rem = s_rem, accum = 0, b;
            for (b = 255; b > 0; --b) {
                if (accum + hist[b] >= rem) break;
                accum += hist[b];
            }
            s_rem = rem - accum;
            s_prefix = prefix | ((unsigned)b << shift);
        }
        __syncthreads();
    }

    if (threadIdx.x == 0) {
        const unsigned u = s_prefix;
        const unsigned orig = (u & 0x80000000u) ? (u & 0x7FFFFFFFu) : ~u;
        thr[row] = __uint_as_float(orig);
    }
}

// ---------------------------------------------------------------------------
__global__ __launch_bounds__(128) void bitpack(const float* __restrict__ Sm,
                                               const float* __restrict__ thr,
                                               unsigned* __restrict__ Abits)
{
    const int row = blockIdx.x;
    const int w = threadIdx.x;
    const float t = thr[row];
    const float* p = Sm + (size_t)row * MSAMP + w * 32;
    unsigned m = 0;
#pragma unroll
    for (int b = 0; b < 32; b += 4) {
        float4 v = *(const float4*)(p + b);
        m |= (v.x >= t ? 1u : 0u) << (b + 0);
        m |= (v.y >= t ? 1u : 0u) << (b + 1);
        m |= (v.z >= t ? 1u : 0u) << (b + 2);
        m |= (v.w >= t ? 1u : 0u) << (b + 3);
    }
    Abits[(size_t)row * (MSAMP / 32) + w] = m;
}

// ---------------------------------------------------------------------------
// XeT_i8[n][m] = clamp(round(Xe[m][n] * 127/6)) — transpose + quantize.
// ---------------------------------------------------------------------------
__global__ void transpose_xe_q(const unsigned short* __restrict__ src,
                               signed char* __restrict__ dst)
{
    __shared__ signed char t[32][36];
    const int bx = blockIdx.x;
    const int by = blockIdx.y;
    const int tx = threadIdx.x, ty = threadIdx.y;
#pragma unroll
    for (int i = 0; i < 4; ++i) {
        float v = h2f(src[(size_t)(by * 32 + ty + 8 * i) * EXPN + bx * 32 + tx]);
        int qv = (int)rintf(v * QSCALE_INV);
        qv = max(-127, min(127, qv));
        t[tx][ty + 8 * i] = (signed char)qv;
    }
    __syncthreads();
    const int tid = ty * 32 + tx;
    const int nl = tid >> 3, mg = (tid & 7) * 4;
    char4 o;
    o.x = t[nl][mg + 0]; o.y = t[nl][mg + 1];
    o.z = t[nl][mg + 2]; o.w = t[nl][mg + 3];
    *(char4*)&dst[(size_t)(bx * 32 + nl) * MSAMP + by * 32 + mg] = o;
}

// ---------------------------------------------------------------------------
extern "C" void kernel_launch(void* const* d_in, const int* in_sizes, int n_in,
                              void* d_out, int out_size, void* d_ws, size_t ws_size,
                              hipStream_t stream)
{
    const float* X  = (const float*)d_in[0];
    const float* Wb = (const float*)d_in[1];
    const float* Wm = (const float*)d_in[2];
    const float* Wc = (const float*)d_in[3];
    const int*   kp = (const int*)d_in[4];
    float* out = (float*)d_out;

    // Workspace (peak ~194 MiB, same envelope as prior rounds):
    //  SEG0 [0,64M)    Xe f16 [4096][8192]
    //  SEG1 [64,128M)  sim P1 f32 (34.6M, dies at combine) -> XeT_i8 (32M)
    //                  -> WmT+WcT f16 (32M) | Pf f16 x3 @+32M (23.4M)
    //  SEG2 [128,192M) prep {Xh 4M, WbT 8M} -> Sm f32 -> Tk f16
    //  [192M..)        Abits (2 MiB), invn, thr
    char* base = (char*)d_ws;
    const size_t SEG = (size_t)64 << 20;
    const size_t need = 3 * SEG + ((size_t)2 << 20) + 65536;
    if (ws_size < need) return;

    unsigned short* Xe   = (unsigned short*)base;
    float*          SimP1= (float*)(base + SEG);                 // 34.6M (sim scratch)
    signed char*    XeTq = (signed char*)(base + SEG);
    unsigned short* WmT  = (unsigned short*)(base + SEG);        // overlay (after gemm_adj)
    unsigned short* WcT  = WmT + (size_t)NPAD * EXPN;            // +16 MiB
    unsigned short* Pf   = (unsigned short*)(base + SEG + ((size_t)32 << 20)); // 3 x 7.8 MiB
    unsigned short* Xh   = (unsigned short*)(base + 2 * SEG);               // 4 MB
    unsigned short* WbT  = Xh + (size_t)MSAMP * D0;                         // 8 MB
    float*          Sm   = (float*)(base + 2 * SEG);             // overlay (after gemm_xe)
    unsigned short* Tk   = (unsigned short*)(base + 2 * SEG);    // overlay (after bitpack)
    unsigned*       Abits= (unsigned*)(base + 3 * SEG);
    float*          invn = (float*)(base + 3 * SEG + ((size_t)2 << 20));
    float*          thr  = invn + MSAMP;

    const dim3 blk(256);

    // 0) prep: X -> f16, Wb -> WbT f16
    cvt_x<<<dim3((MSAMP * D0) / (256 * 8)), blk, 0, stream>>>(X, Xh);
    transpose_wb<<<dim3(EXPN / 32, D0 / 32), dim3(32, 8), 0, stream>>>(Wb, WbT);

    // 1) Xe = X @ Wb (f16 MFMA, K-step 64)
    gemm_xe_mfma<<<dim3(EXPN / 128, MSAMP / 128), blk, 0, stream>>>(Xh, WbT, Xe);

    // 2) row inverse norms
    row_invnorm<<<dim3(MSAMP), blk, 0, stream>>>(Xe, invn);

    // 3) sim, split-K=2: partials (kh=0 -> Sm slots, kh=1 -> SimP1), then
    //    combine (add + invn scale + diag + mirror)
    gemm_sim<<<dim3(528, 2), blk, 0, stream>>>(Xe, Sm, SimP1);
    sim_combine<<<dim3(528), blk, 0, stream>>>(Sm, SimP1, invn);

    // 4) per-row k-th largest threshold (exact f32 radix select)
    topk_thresh<<<dim3(MSAMP), blk, 0, stream>>>(Sm, thr, MSAMP, kp);

    // 5) adjacency bitmask
    bitpack<<<dim3(MSAMP), dim3(128), 0, stream>>>(Sm, thr, Abits);

    // 6) XeT_i8 = quantized Xe^T (into SEG1, over dead SimP1)
    transpose_xe_q<<<dim3(EXPN / 32, MSAMP / 32), dim3(32, 8), 0, stream>>>(Xe, XeTq);

    // 7) Tk = tanh((1/k) Adj @ Xe) via i8 MFMA (K-step 128) — over dead Sm
    gemm_adj_i8<<<dim3(MSAMP / 128, EXPN / 128), blk, 0, stream>>>(Abits, XeTq, Tk, kp);

    // 8) W transposes (f16 NT) into dead XeT region
    transpose_w<<<dim3(EXPN / 32, NPAD / 32), dim3(32, 8), 0, stream>>>(Wm, WmT);
    transpose_w<<<dim3(EXPN / 32, NPAD / 32), dim3(32, 8), 0, stream>>>(Wc, WcT);

    // 9) split-K=4 output GEMM (K-step 64): z=0 -> f32 out, z=1..3 -> f16 partials
    gemm_out_split<<<dim3(NPAD / 128, MSAMP / 128, 4), blk, 0, stream>>>(
        Xe, Tk, WmT, WcT, out, Pf);

    // 10) out += P0+P1+P2 (kernel-boundary-ordered, XCD-safe)
    add_partials<<<dim3((MSAMP * NCLS / 4 + 255) / 256), blk, 0, stream>>>(
        out, Pf, MSAMP * NCLS / 4);
}

// Round 12
// 923.585 us; speedup vs baseline: 1.1284x; 1.1284x over previous
//
#include <hip/hip_runtime.h>
#include <hip/hip_bf16.h>

#define MSAMP 4096
#define D0    512
#define EXPN  8192
#define NCLS  1000
#define NPAD  1024
#define QSCALE     (6.0f / 127.0f)
#define QSCALE_INV (127.0f / 6.0f)

typedef __attribute__((ext_vector_type(8))) _Float16       half8;
typedef __attribute__((ext_vector_type(8))) unsigned short ushort8v;
typedef __attribute__((ext_vector_type(4))) float          f32x4;
typedef __attribute__((ext_vector_type(4))) int            i32x4v;

__device__ __forceinline__ unsigned short f2h(float f) {
    union { _Float16 h; unsigned short u; } c; c.h = (_Float16)f; return c.u;
}
__device__ __forceinline__ float h2f(unsigned short u) {
    union { unsigned short u; _Float16 h; } c; c.u = u; return (float)c.h;
}
__device__ __forceinline__ ushort8v relu8h(ushort8v v) {   // f16 relu: sign bit
#pragma unroll
    for (int j = 0; j < 8; ++j) v[j] = (v[j] & 0x8000u) ? (unsigned short)0 : v[j];
    return v;
}
__device__ __forceinline__ half8 as_half8(const unsigned short* p) {
    return *(const half8*)p;
}
__device__ __forceinline__ float tanh_fast(float x) {
    float e = __expf(2.0f * x);
    return 1.0f - 2.0f * __builtin_amdgcn_rcpf(e + 1.0f);
}
// Bank swizzle (verified R9: conflicts 1.73e7 -> 0): fold bit5 of the 16B-unit
// row index into bit2. Writes fold 4*(tid&1) into l_w; reads fold 4*(lane>=32)
// into lane. Same bijection both sides -> bit-exact.

// ---------------------------------------------------------------------------
// X f32 [4096][512] -> f16
// ---------------------------------------------------------------------------
__global__ __launch_bounds__(256) void cvt_x(const float* __restrict__ src,
                                             unsigned short* __restrict__ dst)
{
    const size_t i = ((size_t)blockIdx.x * 256 + threadIdx.x) * 8;
    float4 v0 = *(const float4*)(src + i), v1 = *(const float4*)(src + i + 4);
    union { unsigned short u[8]; ushort8v v; } H;
    H.u[0] = f2h(v0.x); H.u[1] = f2h(v0.y); H.u[2] = f2h(v0.z); H.u[3] = f2h(v0.w);
    H.u[4] = f2h(v1.x); H.u[5] = f2h(v1.y); H.u[6] = f2h(v1.z); H.u[7] = f2h(v1.w);
    *(ushort8v*)(dst + i) = H.v;
}

// ---------------------------------------------------------------------------
// Wb [512][8192] f32 -> WbT f16 [8192][512]
// ---------------------------------------------------------------------------
__global__ void transpose_wb(const float* __restrict__ src,
                             unsigned short* __restrict__ dst)
{
    __shared__ float t[32][33];
    const int n0 = blockIdx.x * 32, k0 = blockIdx.y * 32;
    const int tx = threadIdx.x, ty = threadIdx.y;
#pragma unroll
    for (int i = 0; i < 4; ++i)
        t[ty + 8 * i][tx] = src[(size_t)(k0 + ty + 8 * i) * EXPN + n0 + tx];
    __syncthreads();
#pragma unroll
    for (int i = 0; i < 4; ++i)
        dst[(size_t)(n0 + ty + 8 * i) * D0 + k0 + tx] = f2h(t[tx][ty + 8 * i]);
}

// ---------------------------------------------------------------------------
// Xe(f16) = X @ Wb via f16 MFMA, NT, K=512. Fragment-major LDS, K-step 64,
// bank-swizzled rows (l_ws/lane_s). (R9 verbatim)
// ---------------------------------------------------------------------------
__global__ __launch_bounds__(256) void gemm_xe_mfma(
    const unsigned short* __restrict__ Xh, const unsigned short* __restrict__ WbT,
    unsigned short* __restrict__ Xe)
{
    __shared__ __align__(16) char smem[34816];
    unsigned short (*AsF)[2][64][8] = (unsigned short (*)[2][64][8])(smem);
    unsigned short (*BsF)[2][64][8] = (unsigned short (*)[2][64][8])(smem + 16384);

    const int tid = threadIdx.x;
    const int wid = tid >> 6, lane = tid & 63;
    const int l15 = lane & 15, q = lane >> 4;
    const int wm = (wid >> 1) * 64, wn = (wid & 1) * 64;
    const int row0 = blockIdx.y * 128, col0 = blockIdx.x * 128;

    const int sr = tid >> 1;
    const int scp = (tid & 1) * 2;
    const int mi_w = sr >> 4;
    const int l_ws = (sr & 15) ^ ((tid & 1) << 2);     // bank-swizzled write row
    const int lane_s = lane ^ ((lane >> 3) & 4);       // bank-swizzled read row

    f32x4 acc[4][4];
#pragma unroll
    for (int m = 0; m < 4; ++m)
#pragma unroll
        for (int n = 0; n < 4; ++n) acc[m][n] = (f32x4){0.f, 0.f, 0.f, 0.f};

    for (int k0 = 0; k0 < D0; k0 += 64) {
        const unsigned short* pa = Xh  + (size_t)(row0 + sr) * D0 + k0 + scp * 8;
        const unsigned short* pb = WbT + (size_t)(col0 + sr) * D0 + k0 + scp * 8;
        ushort8v a0 = *(const ushort8v*)pa,        a1 = *(const ushort8v*)(pa + 8);
        ushort8v a2 = *(const ushort8v*)(pa + 32), a3 = *(const ushort8v*)(pa + 40);
        ushort8v b0 = *(const ushort8v*)pb,        b1 = *(const ushort8v*)(pb + 8);
        ushort8v b2 = *(const ushort8v*)(pb + 32), b3 = *(const ushort8v*)(pb + 40);

        __syncthreads();
        *(ushort8v*)&AsF[mi_w][0][scp * 16 + l_ws][0]       = a0;
        *(ushort8v*)&AsF[mi_w][0][(scp + 1) * 16 + l_ws][0] = a1;
        *(ushort8v*)&AsF[mi_w][1][scp * 16 + l_ws][0]       = a2;
        *(ushort8v*)&AsF[mi_w][1][(scp + 1) * 16 + l_ws][0] = a3;
        *(ushort8v*)&BsF[mi_w][0][scp * 16 + l_ws][0]       = b0;
        *(ushort8v*)&BsF[mi_w][0][(scp + 1) * 16 + l_ws][0] = b1;
        *(ushort8v*)&BsF[mi_w][1][scp * 16 + l_ws][0]       = b2;
        *(ushort8v*)&BsF[mi_w][1][(scp + 1) * 16 + l_ws][0] = b3;
        __syncthreads();

        half8 fa[4][2], fb[4][2];
#pragma unroll
        for (int m = 0; m < 4; ++m) {
            fa[m][0] = as_half8(&AsF[(wm >> 4) + m][0][lane_s][0]);
            fa[m][1] = as_half8(&AsF[(wm >> 4) + m][1][lane_s][0]);
            fb[m][0] = as_half8(&BsF[(wn >> 4) + m][0][lane_s][0]);
            fb[m][1] = as_half8(&BsF[(wn >> 4) + m][1][lane_s][0]);
        }
#pragma unroll
        for (int m = 0; m < 4; ++m)
#pragma unroll
            for (int n = 0; n < 4; ++n) {
                acc[m][n] = __builtin_amdgcn_mfma_f32_16x16x32_f16(fa[m][0], fb[n][0], acc[m][n], 0, 0, 0);
                acc[m][n] = __builtin_amdgcn_mfma_f32_16x16x32_f16(fa[m][1], fb[n][1], acc[m][n], 0, 0, 0);
            }
    }

    unsigned short (*Cb)[136] = (unsigned short (*)[136])smem;
    const int rr = tid >> 1, hh = (tid & 1) * 64;
    __syncthreads();
#pragma unroll
    for (int m = 0; m < 4; ++m)
#pragma unroll
        for (int n = 0; n < 4; ++n)
#pragma unroll
            for (int r = 0; r < 4; ++r)
                Cb[wm + m * 16 + q * 4 + r][wn + n * 16 + l15] = f2h(acc[m][n][r]);
    __syncthreads();
#pragma unroll
    for (int c = 0; c < 8; ++c)
        *(ushort8v*)&Xe[(size_t)(row0 + rr) * EXPN + col0 + hh + c * 8] =
            *(const ushort8v*)&Cb[rr][hh + c * 8];
}

// ---------------------------------------------------------------------------
// sim = (Xe @ Xe^T)*inv_i*inv_j, diag=-3e38. 528 upper-tri blocks + mirror.
// K-step 64, bank-swizzled fragment LDS, DOUBLE-BUFFERED (one barrier/step).
// Grid-limited to ~2 blocks/CU, so 64 KiB LDS costs no residency.
// ---------------------------------------------------------------------------
__global__ __launch_bounds__(256) void gemm_sim(
    const unsigned short* __restrict__ Xe,
    const float* __restrict__ invn, float* __restrict__ Sm)
{
    __shared__ unsigned short AsF[2][8][2][64][8], BsF[2][8][2][64][8];  // 64 KiB

    const int t = blockIdx.x;
    int bj = (int)((sqrtf(8.0f * t + 1.0f) - 1.0f) * 0.5f);
    while ((bj + 1) * (bj + 2) / 2 <= t) ++bj;
    while (bj * (bj + 1) / 2 > t) --bj;
    const int bi = t - bj * (bj + 1) / 2;
    const int row0 = bi * 128, col0 = bj * 128;

    const int tid = threadIdx.x;
    const int wid = tid >> 6, lane = tid & 63;
    const int l15 = lane & 15, q = lane >> 4;
    const int wm = (wid >> 1) * 64, wn = (wid & 1) * 64;

    const int sr = tid >> 1;
    const int scp = (tid & 1) * 2;
    const int mi_w = sr >> 4;
    const int l_ws = (sr & 15) ^ ((tid & 1) << 2);
    const int lane_s = lane ^ ((lane >> 3) & 4);

    const unsigned short* pa0 = Xe + (size_t)(row0 + sr) * EXPN + scp * 8;
    const unsigned short* pb0 = Xe + (size_t)(col0 + sr) * EXPN + scp * 8;

    f32x4 acc[4][4];
#pragma unroll
    for (int m = 0; m < 4; ++m)
#pragma unroll
        for (int n = 0; n < 4; ++n) acc[m][n] = (f32x4){0.f, 0.f, 0.f, 0.f};

    // preload k=0
    ushort8v a0 = *(const ushort8v*)pa0,        a1 = *(const ushort8v*)(pa0 + 8);
    ushort8v a2 = *(const ushort8v*)(pa0 + 32), a3 = *(const ushort8v*)(pa0 + 40);
    ushort8v b0 = *(const ushort8v*)pb0,        b1 = *(const ushort8v*)(pb0 + 8);
    ushort8v b2 = *(const ushort8v*)(pb0 + 32), b3 = *(const ushort8v*)(pb0 + 40);

    int p = 0;
    for (int k0 = 0; k0 < EXPN; k0 += 64) {
        // stage current regs into buf[p] (prev iter's readers use buf[p^1])
        *(ushort8v*)&AsF[p][mi_w][0][scp * 16 + l_ws][0]       = a0;
        *(ushort8v*)&AsF[p][mi_w][0][(scp + 1) * 16 + l_ws][0] = a1;
        *(ushort8v*)&AsF[p][mi_w][1][scp * 16 + l_ws][0]       = a2;
        *(ushort8v*)&AsF[p][mi_w][1][(scp + 1) * 16 + l_ws][0] = a3;
        *(ushort8v*)&BsF[p][mi_w][0][scp * 16 + l_ws][0]       = b0;
        *(ushort8v*)&BsF[p][mi_w][0][(scp + 1) * 16 + l_ws][0] = b1;
        *(ushort8v*)&BsF[p][mi_w][1][scp * 16 + l_ws][0]       = b2;
        *(ushort8v*)&BsF[p][mi_w][1][(scp + 1) * 16 + l_ws][0] = b3;
        __syncthreads();                          // buf[p] ready for all

        if (k0 + 64 < EXPN) {                     // issue next-step loads;
            const int kn = k0 + 64;               // they fly under the MFMAs
            a0 = *(const ushort8v*)(pa0 + kn);        a1 = *(const ushort8v*)(pa0 + kn + 8);
            a2 = *(const ushort8v*)(pa0 + kn + 32);   a3 = *(const ushort8v*)(pa0 + kn + 40);
            b0 = *(const ushort8v*)(pb0 + kn);        b1 = *(const ushort8v*)(pb0 + kn + 8);
            b2 = *(const ushort8v*)(pb0 + kn + 32);   b3 = *(const ushort8v*)(pb0 + kn + 40);
        }

        half8 fa[4][2], fb[4][2];
#pragma unroll
        for (int m = 0; m < 4; ++m) {
            fa[m][0] = as_half8(&AsF[p][(wm >> 4) + m][0][lane_s][0]);
            fa[m][1] = as_half8(&AsF[p][(wm >> 4) + m][1][lane_s][0]);
            fb[m][0] = as_half8(&BsF[p][(wn >> 4) + m][0][lane_s][0]);
            fb[m][1] = as_half8(&BsF[p][(wn >> 4) + m][1][lane_s][0]);
        }
#pragma unroll
        for (int m = 0; m < 4; ++m)
#pragma unroll
            for (int n = 0; n < 4; ++n) {
                acc[m][n] = __builtin_amdgcn_mfma_f32_16x16x32_f16(fa[m][0], fb[n][0], acc[m][n], 0, 0, 0);
                acc[m][n] = __builtin_amdgcn_mfma_f32_16x16x32_f16(fa[m][1], fb[n][1], acc[m][n], 0, 0, 0);
            }
        p ^= 1;
    }

    const bool mirror = (bi != bj);
#pragma unroll
    for (int m = 0; m < 4; ++m)
#pragma unroll
        for (int n = 0; n < 4; ++n) {
            const int gj = col0 + wn + n * 16 + l15;
            const float invj = invn[gj];
#pragma unroll
            for (int r = 0; r < 4; ++r) {
                const int gi = row0 + wm + m * 16 + q * 4 + r;
                float v = acc[m][n][r] * invn[gi] * invj;
                if (gi == gj) v = -3.0e38f;
                Sm[(size_t)gi * MSAMP + gj] = v;
                if (mirror) Sm[(size_t)gj * MSAMP + gi] = v;
            }
        }
}

// ---------------------------------------------------------------------------
// Tk(f16) = tanh((1/k) * Adj @ Xe) via i8 MFMA. K-step 128 (2 x 64),
// bank-swizzled fragment LDS. XCD chunked swizzle (2048 = 8*256). (R9 verbatim)
// ---------------------------------------------------------------------------
__global__ __launch_bounds__(256) void gemm_adj_i8(
    const unsigned* __restrict__ Abits, const signed char* __restrict__ XeT,
    unsigned short* __restrict__ Tk, const int* __restrict__ kp)
{
    __shared__ signed char BsF[8][2][64][16];    // 32 KiB
    __shared__ uint4 aw4[128];

    const int tid = threadIdx.x;
    const int wid = tid >> 6, lane = tid & 63;
    const int l15 = lane & 15, q = lane >> 4;
    const int wm = (wid >> 1) * 64, wn = (wid & 1) * 64;

    const int orig = blockIdx.x + blockIdx.y * 32;   // grid (32, 64), 2048 blocks
    const int s = (orig & 7) * 256 + (orig >> 3);    // bijective XCD chunking
    const int row0 = (s & 31) * 128;                 // sample rows
    const int col0 = (s >> 5) * 128;                 // expansion cols

    const int sr = tid >> 1;
    const int half = tid & 1;
    const int l_ws = (sr & 15) ^ (half << 2);
    const int lane_s = lane ^ ((lane >> 3) & 4);

    i32x4v acc[4][4];
#pragma unroll
    for (int m = 0; m < 4; ++m)
#pragma unroll
        for (int n = 0; n < 4; ++n) acc[m][n] = (i32x4v){0, 0, 0, 0};

    for (int k0 = 0; k0 < MSAMP; k0 += 128) {
        const signed char* pb = XeT + (size_t)(col0 + sr) * MSAMP + k0 + half * 32;
        i32x4v b0 = *(const i32x4v*)pb;
        i32x4v b1 = *(const i32x4v*)(pb + 16);
        i32x4v b2 = *(const i32x4v*)(pb + 64);
        i32x4v b3 = *(const i32x4v*)(pb + 80);
        uint4 wv = make_uint4(0u, 0u, 0u, 0u);
        if (tid < 128)
            wv = *(const uint4*)(Abits + (size_t)(row0 + tid) * (MSAMP / 32) + (k0 >> 5));

        __syncthreads();
        *(i32x4v*)&BsF[sr >> 4][0][(half * 2 + 0) * 16 + l_ws][0] = b0;
        *(i32x4v*)&BsF[sr >> 4][0][(half * 2 + 1) * 16 + l_ws][0] = b1;
        *(i32x4v*)&BsF[sr >> 4][1][(half * 2 + 0) * 16 + l_ws][0] = b2;
        *(i32x4v*)&BsF[sr >> 4][1][(half * 2 + 1) * 16 + l_ws][0] = b3;
        if (tid < 128) aw4[tid] = wv;
        __syncthreads();

        i32x4v fb[4][2];
#pragma unroll
        for (int n = 0; n < 4; ++n) {
            fb[n][0] = *(const i32x4v*)&BsF[(wn >> 4) + n][0][lane_s][0];
            fb[n][1] = *(const i32x4v*)&BsF[(wn >> 4) + n][1][lane_s][0];
        }

#pragma unroll
        for (int m = 0; m < 4; ++m) {
            const uint4 ww = aw4[wm + m * 16 + l15];
#pragma unroll
            for (int kh = 0; kh < 2; ++kh) {
                const unsigned w = (kh == 0) ? ((q >= 2) ? ww.y : ww.x)
                                             : ((q >= 2) ? ww.w : ww.z);
                const unsigned hw = (q & 1) ? (w >> 16) : w;
                i32x4v fa;
#pragma unroll
                for (int p = 0; p < 4; ++p)
                    fa[p] = (int)((((hw >> (4 * p)) & 0xFu) * 0x00204081u) & 0x01010101u);
#pragma unroll
                for (int n = 0; n < 4; ++n)
                    acc[m][n] = __builtin_amdgcn_mfma_i32_16x16x64_i8(fa, fb[n][kh], acc[m][n], 0, 0, 0);
            }
        }
    }

    const float kv = QSCALE / (float)(*kp);
#pragma unroll
    for (int m = 0; m < 4; ++m)
#pragma unroll
        for (int n = 0; n < 4; ++n) {
            const int gj = col0 + wn + n * 16 + l15;
#pragma unroll
            for (int r = 0; r < 4; ++r) {
                const int gi = row0 + wm + m * 16 + q * 4 + r;
                Tk[(size_t)gi * EXPN + gj] = f2h(tanh_fast((float)acc[m][n][r] * kv));
            }
        }
}

// ---------------------------------------------------------------------------
// W [8192][1000] f32 -> WT f16 [NPAD][8192], zero-padded rows.
// ---------------------------------------------------------------------------
__global__ void transpose_w(const float* __restrict__ src,
                            unsigned short* __restrict__ dst)
{
    __shared__ float t[32][33];
    const int k0 = blockIdx.x * 32, n0 = blockIdx.y * 32;
    const int tx = threadIdx.x, ty = threadIdx.y;
#pragma unroll
    for (int i = 0; i < 4; ++i) {
        const int n = n0 + tx;
        t[ty + 8 * i][tx] = (n < NCLS) ? src[(size_t)(k0 + ty + 8 * i) * NCLS + n] : 0.f;
    }
    __syncthreads();
#pragma unroll
    for (int i = 0; i < 4; ++i)
        dst[(size_t)(n0 + ty + 8 * i) * EXPN + k0 + tx] = f2h(t[tx][ty + 8 * i]);
}

// ---------------------------------------------------------------------------
// Split-K=4, NO atomics. XCD chunked swizzle on (x,y), z preserved.
// K-step 64 (2 x 32), bank-swizzled fragment LDS, relu at ds_write time (z<2).
// (R9 verbatim)
// ---------------------------------------------------------------------------
__global__ __launch_bounds__(256) void gemm_out_split(
    const unsigned short* __restrict__ Xe, const unsigned short* __restrict__ Tk,
    const unsigned short* __restrict__ WmT, const unsigned short* __restrict__ WcT,
    float* __restrict__ Cout, unsigned short* __restrict__ Pf)
{
    __shared__ unsigned short AsF[8][2][64][8], BsF[8][2][64][8];   // 32 KiB

    const int tid = threadIdx.x;
    const int wid = tid >> 6, lane = tid & 63;
    const int l15 = lane & 15, q = lane >> 4;
    const int wm = (wid >> 1) * 64, wn = (wid & 1) * 64;

    const int orig = blockIdx.x + blockIdx.y * 8;    // 256 blocks per z
    const int s = (orig & 7) * 32 + (orig >> 3);     // bijective XCD chunking
    const int col0 = (s & 7) * 128;
    const int row0 = (s >> 3) * 128;
    const int zz = blockIdx.z;
    const bool xe_side = (zz < 2);
    const int kbase = (zz & 1) * (EXPN / 2);

    const unsigned short* Abase = xe_side ? Xe : Tk;
    const unsigned short* Bbase = xe_side ? WmT : WcT;

    const int sr = tid >> 1;
    const int scp = (tid & 1) * 2;
    const int mi_w = sr >> 4;
    const int l_ws = (sr & 15) ^ ((tid & 1) << 2);
    const int lane_s = lane ^ ((lane >> 3) & 4);

    f32x4 acc[4][4];
#pragma unroll
    for (int m = 0; m < 4; ++m)
#pragma unroll
        for (int n = 0; n < 4; ++n) acc[m][n] = (f32x4){0.f, 0.f, 0.f, 0.f};

    for (int kk = 0; kk < EXPN / 2; kk += 64) {
        const int k0 = kbase + kk;
        const unsigned short* pa = Abase + (size_t)(row0 + sr) * EXPN + k0 + scp * 8;
        const unsigned short* pb = Bbase + (size_t)(col0 + sr) * EXPN + k0 + scp * 8;
        ushort8v a0 = *(const ushort8v*)pa,        a1 = *(const ushort8v*)(pa + 8);
        ushort8v a2 = *(const ushort8v*)(pa + 32), a3 = *(const ushort8v*)(pa + 40);
        ushort8v b0 = *(const ushort8v*)pb,        b1 = *(const ushort8v*)(pb + 8);
        ushort8v b2 = *(const ushort8v*)(pb + 32), b3 = *(const ushort8v*)(pb + 40);
        if (xe_side) { a0 = relu8h(a0); a1 = relu8h(a1); a2 = relu8h(a2); a3 = relu8h(a3); }

        __syncthreads();
        *(ushort8v*)&AsF[mi_w][0][scp * 16 + l_ws][0]       = a0;
        *(ushort8v*)&AsF[mi_w][0][(scp + 1) * 16 + l_ws][0] = a1;
        *(ushort8v*)&AsF[mi_w][1][scp * 16 + l_ws][0]       = a2;
        *(ushort8v*)&AsF[mi_w][1][(scp + 1) * 16 + l_ws][0] = a3;
        *(ushort8v*)&BsF[mi_w][0][scp * 16 + l_ws][0]       = b0;
        *(ushort8v*)&BsF[mi_w][0][(scp + 1) * 16 + l_ws][0] = b1;
        *(ushort8v*)&BsF[mi_w][1][scp * 16 + l_ws][0]       = b2;
        *(ushort8v*)&BsF[mi_w][1][(scp + 1) * 16 + l_ws][0] = b3;
        __syncthreads();

        half8 fa[4][2], fb[4][2];
#pragma unroll
        for (int m = 0; m < 4; ++m) {
            fa[m][0] = as_half8(&AsF[(wm >> 4) + m][0][lane_s][0]);
            fa[m][1] = as_half8(&AsF[(wm >> 4) + m][1][lane_s][0]);
            fb[m][0] = as_half8(&BsF[(wn >> 4) + m][0][lane_s][0]);
            fb[m][1] = as_half8(&BsF[(wn >> 4) + m][1][lane_s][0]);
        }
#pragma unroll
        for (int m = 0; m < 4; ++m)
#pragma unroll
            for (int n = 0; n < 4; ++n) {
                acc[m][n] = __builtin_amdgcn_mfma_f32_16x16x32_f16(fa[m][0], fb[n][0], acc[m][n], 0, 0, 0);
                acc[m][n] = __builtin_amdgcn_mfma_f32_16x16x32_f16(fa[m][1], fb[n][1], acc[m][n], 0, 0, 0);
            }
    }

    if (zz == 0) {
#pragma unroll
        for (int m = 0; m < 4; ++m)
#pragma unroll
            for (int n = 0; n < 4; ++n) {
                const int gj = col0 + wn + n * 16 + l15;
                if (gj < NCLS) {
#pragma unroll
                    for (int r = 0; r < 4; ++r) {
                        const int gi = row0 + wm + m * 16 + q * 4 + r;
                        Cout[(size_t)gi * NCLS + gj] = acc[m][n][r];
                    }
                }
            }
    } else {
        unsigned short* dp = Pf + (size_t)(zz - 1) * MSAMP * NCLS;
#pragma unroll
        for (int m = 0; m < 4; ++m)
#pragma unroll
            for (int n = 0; n < 4; ++n) {
                const int gj = col0 + wn + n * 16 + l15;
                if (gj < NCLS) {
#pragma unroll
                    for (int r = 0; r < 4; ++r) {
                        const int gi = row0 + wm + m * 16 + q * 4 + r;
                        dp[(size_t)gi * NCLS + gj] = f2h(acc[m][n][r]);
                    }
                }
            }
    }
}

// ---------------------------------------------------------------------------
// out[i] += P0[i] + P1[i] + P2[i]   (f16 partials -> f32 accumulate)
// ---------------------------------------------------------------------------
__global__ __launch_bounds__(256) void add_partials(float* __restrict__ out,
                                                    const unsigned short* __restrict__ P,
                                                    int n4)
{
    const int i = blockIdx.x * 256 + threadIdx.x;
    if (i < n4) {
        float4 a = ((const float4*)out)[i];
        const ushort4 p0 = *(const ushort4*)(P + (size_t)i * 4);
        const ushort4 p1 = *(const ushort4*)(P + (size_t)MSAMP * NCLS + (size_t)i * 4);
        const ushort4 p2 = *(const ushort4*)(P + (size_t)2 * MSAMP * NCLS + (size_t)i * 4);
        a.x += h2f(p0.x) + h2f(p1.x) + h2f(p2.x);
        a.y += h2f(p0.y) + h2f(p1.y) + h2f(p2.y);
        a.z += h2f(p0.z) + h2f(p1.z) + h2f(p2.z);
        a.w += h2f(p0.w) + h2f(p1.w) + h2f(p2.w);
        ((float4*)out)[i] = a;
    }
}

// ---------------------------------------------------------------------------
__global__ __launch_bounds__(256) void row_invnorm(
    const unsigned short* __restrict__ Xe, float* __restrict__ invn)
{
    const int row = blockIdx.x;
    float s = 0.f;
    for (int j = threadIdx.x * 8; j < EXPN; j += 2048) {
        ushort8v h = *(const ushort8v*)(Xe + (size_t)row * EXPN + j);
#pragma unroll
        for (int c = 0; c < 8; ++c) { float x = h2f(h[c]); s += x * x; }
    }
#pragma unroll
    for (int off = 32; off > 0; off >>= 1) s += __shfl_down(s, off);
    __shared__ float wsum[4];
    if ((threadIdx.x & 63) == 0) wsum[threadIdx.x >> 6] = s;
    __syncthreads();
    if (threadIdx.x == 0)
        invn[row] = rsqrtf(wsum[0] + wsum[1] + wsum[2] + wsum[3]);
}

// ---------------------------------------------------------------------------
__global__ __launch_bounds__(256) void topk_thresh(const float* __restrict__ sim,
                                                   float* __restrict__ thr,
                                                   int N, const int* __restrict__ kp)
{
    const int row = blockIdx.x;
    const float* srow = sim + (size_t)row * N;
    __shared__ int hist[256];
    __shared__ unsigned s_prefix;
    __shared__ int s_rem;
    if (threadIdx.x == 0) { s_prefix = 0u; s_rem = *kp; }
    __syncthreads();

    for (int pass = 0; pass < 4; ++pass) {
        const int shift = 24 - 8 * pass;
        hist[threadIdx.x] = 0;
        __syncthreads();
        const unsigned prefix = s_prefix;
        const unsigned pmask = (pass == 0) ? 0u : (0xFFFFFFFFu << (shift + 8));
        for (int j = threadIdx.x; j < N; j += 256) {
            unsigned u = __float_as_uint(srow[j]);
            u = ((int)u < 0) ? ~u : (u | 0x80000000u);
            if ((u & pmask) == (prefix & pmask))
                atomicAdd(&hist[(u >> shift) & 255], 1);
        }
        __syncthreads();
        if (threadIdx.x == 0) {
            int rem = s_rem, accum = 0, b;
            for (b = 255; b > 0; --b) {
                if (accum + hist[b] >= rem) break;
                accum += hist[b];
            }
            s_rem = rem - accum;
            s_prefix = prefix | ((unsigned)b << shift);
        }
        __syncthreads();
    }

    if (threadIdx.x == 0) {
        const unsigned u = s_prefix;
        const unsigned orig = (u & 0x80000000u) ? (u & 0x7FFFFFFFu) : ~u;
        thr[row] = __uint_as_float(orig);
    }
}

// ---------------------------------------------------------------------------
__global__ __launch_bounds__(128) void bitpack(const float* __restrict__ Sm,
                                               const float* __restrict__ thr,
                                               unsigned* __restrict__ Abits)
{
    const int row = blockIdx.x;
    const int w = threadIdx.x;
    const float t = thr[row];
    const float* p = Sm + (size_t)row * MSAMP + w * 32;
    unsigned m = 0;
#pragma unroll
    for (int b = 0; b < 32; b += 4) {
        float4 v = *(const float4*)(p + b);
        m |= (v.x >= t ? 1u : 0u) << (b + 0);
        m |= (v.y >= t ? 1u : 0u) << (b + 1);
        m |= (v.z >= t ? 1u : 0u) << (b + 2);
        m |= (v.w >= t ? 1u : 0u) << (b + 3);
    }
    Abits[(size_t)row * (MSAMP / 32) + w] = m;
}

// ---------------------------------------------------------------------------
// XeT_i8[n][m] = clamp(round(Xe[m][n] * 127/6)) — transpose + quantize.
// ---------------------------------------------------------------------------
__global__ void transpose_xe_q(const unsigned short* __restrict__ src,
                               signed char* __restrict__ dst)
{
    __shared__ signed char t[32][36];
    const int bx = blockIdx.x;
    const int by = blockIdx.y;
    const int tx = threadIdx.x, ty = threadIdx.y;
#pragma unroll
    for (int i = 0; i < 4; ++i) {
        float v = h2f(src[(size_t)(by * 32 + ty + 8 * i) * EXPN + bx * 32 + tx]);
        int qv = (int)rintf(v * QSCALE_INV);
        qv = max(-127, min(127, qv));
        t[tx][ty + 8 * i] = (signed char)qv;
    }
    __syncthreads();
    const int tid = ty * 32 + tx;
    const int nl = tid >> 3, mg = (tid & 7) * 4;
    char4 o;
    o.x = t[nl][mg + 0]; o.y = t[nl][mg + 1];
    o.z = t[nl][mg + 2]; o.w = t[nl][mg + 3];
    *(char4*)&dst[(size_t)(bx * 32 + nl) * MSAMP + by * 32 + mg] = o;
}

// ---------------------------------------------------------------------------
extern "C" void kernel_launch(void* const* d_in, const int* in_sizes, int n_in,
                              void* d_out, int out_size, void* d_ws, size_t ws_size,
                              hipStream_t stream)
{
    const float* X  = (const float*)d_in[0];
    const float* Wb = (const float*)d_in[1];
    const float* Wm = (const float*)d_in[2];
    const float* Wc = (const float*)d_in[3];
    const int*   kp = (const int*)d_in[4];
    float* out = (float*)d_out;

    // Workspace (peak ~194 MiB, same envelope as prior rounds):
    //  SEG0 [0,64M)    Xe f16 [4096][8192]
    //  SEG1 [64,128M)  XeT_i8 (32M) -> WmT+WcT f16 (32M) | Pf f16 x3 @+32M (23.4M)
    //  SEG2 [128,192M) prep {Xh 4M, WbT 8M} -> Sm f32 -> Tk f16
    //  [192M..)        Abits (2 MiB), invn, thr
    char* base = (char*)d_ws;
    const size_t SEG = (size_t)64 << 20;
    const size_t need = 3 * SEG + ((size_t)2 << 20) + 65536;
    if (ws_size < need) return;

    unsigned short* Xe   = (unsigned short*)base;
    signed char*    XeTq = (signed char*)(base + SEG);
    unsigned short* WmT  = (unsigned short*)(base + SEG);        // overlay (after gemm_adj)
    unsigned short* WcT  = WmT + (size_t)NPAD * EXPN;            // +16 MiB
    unsigned short* Pf   = (unsigned short*)(base + SEG + ((size_t)32 << 20)); // 3 x 7.8 MiB
    unsigned short* Xh   = (unsigned short*)(base + 2 * SEG);               // 4 MB
    unsigned short* WbT  = Xh + (size_t)MSAMP * D0;                         // 8 MB
    float*          Sm   = (float*)(base + 2 * SEG);             // overlay (after gemm_xe)
    unsigned short* Tk   = (unsigned short*)(base + 2 * SEG);    // overlay (after bitpack)
    unsigned*       Abits= (unsigned*)(base + 3 * SEG);
    float*          invn = (float*)(base + 3 * SEG + ((size_t)2 << 20));
    float*          thr  = invn + MSAMP;

    const dim3 blk(256);

    // 0) prep: X -> f16, Wb -> WbT f16
    cvt_x<<<dim3((MSAMP * D0) / (256 * 8)), blk, 0, stream>>>(X, Xh);
    transpose_wb<<<dim3(EXPN / 32, D0 / 32), dim3(32, 8), 0, stream>>>(Wb, WbT);

    // 1) Xe = X @ Wb (f16 MFMA, K-step 64)
    gemm_xe_mfma<<<dim3(EXPN / 128, MSAMP / 128), blk, 0, stream>>>(Xh, WbT, Xe);

    // 2) row inverse norms
    row_invnorm<<<dim3(MSAMP), blk, 0, stream>>>(Xe, invn);

    // 3) sim (symmetric: 528 upper-tri blocks, mirrored writes, K-step 64, dbuf)
    gemm_sim<<<dim3(528), blk, 0, stream>>>(Xe, invn, Sm);

    // 4) per-row k-th largest threshold (exact f32 radix select)
    topk_thresh<<<dim3(MSAMP), blk, 0, stream>>>(Sm, thr, MSAMP, kp);

    // 5) adjacency bitmask
    bitpack<<<dim3(MSAMP), dim3(128), 0, stream>>>(Sm, thr, Abits);

    // 6) XeT_i8 = quantized Xe^T (into SEG1)
    transpose_xe_q<<<dim3(EXPN / 32, MSAMP / 32), dim3(32, 8), 0, stream>>>(Xe, XeTq);

    // 7) Tk = tanh((1/k) Adj @ Xe) via i8 MFMA (K-step 128) — over dead Sm
    gemm_adj_i8<<<dim3(MSAMP / 128, EXPN / 128), blk, 0, stream>>>(Abits, XeTq, Tk, kp);

    // 8) W transposes (f16 NT) into dead XeT region
    transpose_w<<<dim3(EXPN / 32, NPAD / 32), dim3(32, 8), 0, stream>>>(Wm, WmT);
    transpose_w<<<dim3(EXPN / 32, NPAD / 32), dim3(32, 8), 0, stream>>>(Wc, WcT);

    // 9) split-K=4 output GEMM (K-step 64): z=0 -> f32 out, z=1..3 -> f16 partials
    gemm_out_split<<<dim3(NPAD / 128, MSAMP / 128, 4), blk, 0, stream>>>(
        Xe, Tk, WmT, WcT, out, Pf);

    // 10) out += P0+P1+P2 (kernel-boundary-ordered, XCD-safe)
    add_partials<<<dim3((MSAMP * NCLS / 4 + 255) / 256), blk, 0, stream>>>(
        out, Pf, MSAMP * NCLS / 4);
}

// Round 13
// 883.133 us; speedup vs baseline: 1.1801x; 1.0458x over previous
//
#include <hip/hip_runtime.h>
#include <hip/hip_bf16.h>

#define MSAMP 4096
#define D0    512
#define EXPN  8192
#define NCLS  1000
#define NPAD  1024
#define QSCALE     (6.0f / 127.0f)
#define QSCALE_INV (127.0f / 6.0f)

typedef __attribute__((ext_vector_type(8))) _Float16       half8;
typedef __attribute__((ext_vector_type(8))) unsigned short ushort8v;
typedef __attribute__((ext_vector_type(4))) float          f32x4;
typedef __attribute__((ext_vector_type(4))) int            i32x4v;

__device__ __forceinline__ unsigned short f2h(float f) {
    union { _Float16 h; unsigned short u; } c; c.h = (_Float16)f; return c.u;
}
__device__ __forceinline__ float h2f(unsigned short u) {
    union { unsigned short u; _Float16 h; } c; c.u = u; return (float)c.h;
}
__device__ __forceinline__ ushort8v relu8h(ushort8v v) {   // f16 relu: sign bit
#pragma unroll
    for (int j = 0; j < 8; ++j) v[j] = (v[j] & 0x8000u) ? (unsigned short)0 : v[j];
    return v;
}
__device__ __forceinline__ half8 as_half8(const unsigned short* p) {
    return *(const half8*)p;
}
__device__ __forceinline__ float tanh_fast(float x) {
    float e = __expf(2.0f * x);
    return 1.0f - 2.0f * __builtin_amdgcn_rcpf(e + 1.0f);
}
// Bank swizzle (verified R9: conflicts 1.73e7 -> 0): fold bit5 of the 16B-unit
// row index into bit2. Writes fold 4*(tid&1) into l_w; reads fold 4*(lane>=32)
// into lane. Same bijection both sides -> bit-exact.

// ---------------------------------------------------------------------------
// X f32 [4096][512] -> f16
// ---------------------------------------------------------------------------
__global__ __launch_bounds__(256) void cvt_x(const float* __restrict__ src,
                                             unsigned short* __restrict__ dst)
{
    const size_t i = ((size_t)blockIdx.x * 256 + threadIdx.x) * 8;
    float4 v0 = *(const float4*)(src + i), v1 = *(const float4*)(src + i + 4);
    union { unsigned short u[8]; ushort8v v; } H;
    H.u[0] = f2h(v0.x); H.u[1] = f2h(v0.y); H.u[2] = f2h(v0.z); H.u[3] = f2h(v0.w);
    H.u[4] = f2h(v1.x); H.u[5] = f2h(v1.y); H.u[6] = f2h(v1.z); H.u[7] = f2h(v1.w);
    *(ushort8v*)(dst + i) = H.v;
}

// ---------------------------------------------------------------------------
// Wb [512][8192] f32 -> WbT f16 [8192][512]
// ---------------------------------------------------------------------------
__global__ void transpose_wb(const float* __restrict__ src,
                             unsigned short* __restrict__ dst)
{
    __shared__ float t[32][33];
    const int n0 = blockIdx.x * 32, k0 = blockIdx.y * 32;
    const int tx = threadIdx.x, ty = threadIdx.y;
#pragma unroll
    for (int i = 0; i < 4; ++i)
        t[ty + 8 * i][tx] = src[(size_t)(k0 + ty + 8 * i) * EXPN + n0 + tx];
    __syncthreads();
#pragma unroll
    for (int i = 0; i < 4; ++i)
        dst[(size_t)(n0 + ty + 8 * i) * D0 + k0 + tx] = f2h(t[tx][ty + 8 * i]);
}

// ---------------------------------------------------------------------------
// Xe(f16) = X @ Wb via f16 MFMA, NT, K=512. Fragment-major LDS, K-step 64,
// bank-swizzled rows (l_ws/lane_s).
// ---------------------------------------------------------------------------
__global__ __launch_bounds__(256) void gemm_xe_mfma(
    const unsigned short* __restrict__ Xh, const unsigned short* __restrict__ WbT,
    unsigned short* __restrict__ Xe)
{
    __shared__ __align__(16) char smem[34816];
    unsigned short (*AsF)[2][64][8] = (unsigned short (*)[2][64][8])(smem);
    unsigned short (*BsF)[2][64][8] = (unsigned short (*)[2][64][8])(smem + 16384);

    const int tid = threadIdx.x;
    const int wid = tid >> 6, lane = tid & 63;
    const int l15 = lane & 15, q = lane >> 4;
    const int wm = (wid >> 1) * 64, wn = (wid & 1) * 64;
    const int row0 = blockIdx.y * 128, col0 = blockIdx.x * 128;

    const int sr = tid >> 1;
    const int scp = (tid & 1) * 2;
    const int mi_w = sr >> 4;
    const int l_ws = (sr & 15) ^ ((tid & 1) << 2);     // bank-swizzled write row
    const int lane_s = lane ^ ((lane >> 3) & 4);       // bank-swizzled read row

    f32x4 acc[4][4];
#pragma unroll
    for (int m = 0; m < 4; ++m)
#pragma unroll
        for (int n = 0; n < 4; ++n) acc[m][n] = (f32x4){0.f, 0.f, 0.f, 0.f};

    for (int k0 = 0; k0 < D0; k0 += 64) {
        const unsigned short* pa = Xh  + (size_t)(row0 + sr) * D0 + k0 + scp * 8;
        const unsigned short* pb = WbT + (size_t)(col0 + sr) * D0 + k0 + scp * 8;
        ushort8v a0 = *(const ushort8v*)pa,        a1 = *(const ushort8v*)(pa + 8);
        ushort8v a2 = *(const ushort8v*)(pa + 32), a3 = *(const ushort8v*)(pa + 40);
        ushort8v b0 = *(const ushort8v*)pb,        b1 = *(const ushort8v*)(pb + 8);
        ushort8v b2 = *(const ushort8v*)(pb + 32), b3 = *(const ushort8v*)(pb + 40);

        __syncthreads();
        *(ushort8v*)&AsF[mi_w][0][scp * 16 + l_ws][0]       = a0;
        *(ushort8v*)&AsF[mi_w][0][(scp + 1) * 16 + l_ws][0] = a1;
        *(ushort8v*)&AsF[mi_w][1][scp * 16 + l_ws][0]       = a2;
        *(ushort8v*)&AsF[mi_w][1][(scp + 1) * 16 + l_ws][0] = a3;
        *(ushort8v*)&BsF[mi_w][0][scp * 16 + l_ws][0]       = b0;
        *(ushort8v*)&BsF[mi_w][0][(scp + 1) * 16 + l_ws][0] = b1;
        *(ushort8v*)&BsF[mi_w][1][scp * 16 + l_ws][0]       = b2;
        *(ushort8v*)&BsF[mi_w][1][(scp + 1) * 16 + l_ws][0] = b3;
        __syncthreads();

        half8 fa[4][2], fb[4][2];
#pragma unroll
        for (int m = 0; m < 4; ++m) {
            fa[m][0] = as_half8(&AsF[(wm >> 4) + m][0][lane_s][0]);
            fa[m][1] = as_half8(&AsF[(wm >> 4) + m][1][lane_s][0]);
            fb[m][0] = as_half8(&BsF[(wn >> 4) + m][0][lane_s][0]);
            fb[m][1] = as_half8(&BsF[(wn >> 4) + m][1][lane_s][0]);
        }
#pragma unroll
        for (int m = 0; m < 4; ++m)
#pragma unroll
            for (int n = 0; n < 4; ++n) {
                acc[m][n] = __builtin_amdgcn_mfma_f32_16x16x32_f16(fa[m][0], fb[n][0], acc[m][n], 0, 0, 0);
                acc[m][n] = __builtin_amdgcn_mfma_f32_16x16x32_f16(fa[m][1], fb[n][1], acc[m][n], 0, 0, 0);
            }
    }

    unsigned short (*Cb)[136] = (unsigned short (*)[136])smem;
    const int rr = tid >> 1, hh = (tid & 1) * 64;
    __syncthreads();
#pragma unroll
    for (int m = 0; m < 4; ++m)
#pragma unroll
        for (int n = 0; n < 4; ++n)
#pragma unroll
            for (int r = 0; r < 4; ++r)
                Cb[wm + m * 16 + q * 4 + r][wn + n * 16 + l15] = f2h(acc[m][n][r]);
    __syncthreads();
#pragma unroll
    for (int c = 0; c < 8; ++c)
        *(ushort8v*)&Xe[(size_t)(row0 + rr) * EXPN + col0 + hh + c * 8] =
            *(const ushort8v*)&Cb[rr][hh + c * 8];
}

// ---------------------------------------------------------------------------
// sim = (Xe @ Xe^T)*inv_i*inv_j, diag=-3e38. 528 upper-tri blocks + mirror.
// K-step 64, bank-swizzled fragment LDS. No XCD swizzle. (R9 verbatim —
// dbuf/split-K/DMA/K=128 all falsified; this is the verified optimum.)
// ---------------------------------------------------------------------------
__global__ __launch_bounds__(256) void gemm_sim(
    const unsigned short* __restrict__ Xe,
    const float* __restrict__ invn, float* __restrict__ Sm)
{
    __shared__ unsigned short AsF[8][2][64][8], BsF[8][2][64][8];   // 32 KiB

    const int t = blockIdx.x;
    int bj = (int)((sqrtf(8.0f * t + 1.0f) - 1.0f) * 0.5f);
    while ((bj + 1) * (bj + 2) / 2 <= t) ++bj;
    while (bj * (bj + 1) / 2 > t) --bj;
    const int bi = t - bj * (bj + 1) / 2;
    const int row0 = bi * 128, col0 = bj * 128;

    const int tid = threadIdx.x;
    const int wid = tid >> 6, lane = tid & 63;
    const int l15 = lane & 15, q = lane >> 4;
    const int wm = (wid >> 1) * 64, wn = (wid & 1) * 64;

    const int sr = tid >> 1;
    const int scp = (tid & 1) * 2;
    const int mi_w = sr >> 4;
    const int l_ws = (sr & 15) ^ ((tid & 1) << 2);
    const int lane_s = lane ^ ((lane >> 3) & 4);

    f32x4 acc[4][4];
#pragma unroll
    for (int m = 0; m < 4; ++m)
#pragma unroll
        for (int n = 0; n < 4; ++n) acc[m][n] = (f32x4){0.f, 0.f, 0.f, 0.f};

    for (int k0 = 0; k0 < EXPN; k0 += 64) {
        const unsigned short* pa = Xe + (size_t)(row0 + sr) * EXPN + k0 + scp * 8;
        const unsigned short* pb = Xe + (size_t)(col0 + sr) * EXPN + k0 + scp * 8;
        ushort8v a0 = *(const ushort8v*)pa,        a1 = *(const ushort8v*)(pa + 8);
        ushort8v a2 = *(const ushort8v*)(pa + 32), a3 = *(const ushort8v*)(pa + 40);
        ushort8v b0 = *(const ushort8v*)pb,        b1 = *(const ushort8v*)(pb + 8);
        ushort8v b2 = *(const ushort8v*)(pb + 32), b3 = *(const ushort8v*)(pb + 40);

        __syncthreads();
        *(ushort8v*)&AsF[mi_w][0][scp * 16 + l_ws][0]       = a0;
        *(ushort8v*)&AsF[mi_w][0][(scp + 1) * 16 + l_ws][0] = a1;
        *(ushort8v*)&AsF[mi_w][1][scp * 16 + l_ws][0]       = a2;
        *(ushort8v*)&AsF[mi_w][1][(scp + 1) * 16 + l_ws][0] = a3;
        *(ushort8v*)&BsF[mi_w][0][scp * 16 + l_ws][0]       = b0;
        *(ushort8v*)&BsF[mi_w][0][(scp + 1) * 16 + l_ws][0] = b1;
        *(ushort8v*)&BsF[mi_w][1][scp * 16 + l_ws][0]       = b2;
        *(ushort8v*)&BsF[mi_w][1][(scp + 1) * 16 + l_ws][0] = b3;
        __syncthreads();

        half8 fa[4][2], fb[4][2];
#pragma unroll
        for (int m = 0; m < 4; ++m) {
            fa[m][0] = as_half8(&AsF[(wm >> 4) + m][0][lane_s][0]);
            fa[m][1] = as_half8(&AsF[(wm >> 4) + m][1][lane_s][0]);
            fb[m][0] = as_half8(&BsF[(wn >> 4) + m][0][lane_s][0]);
            fb[m][1] = as_half8(&BsF[(wn >> 4) + m][1][lane_s][0]);
        }
#pragma unroll
        for (int m = 0; m < 4; ++m)
#pragma unroll
            for (int n = 0; n < 4; ++n) {
                acc[m][n] = __builtin_amdgcn_mfma_f32_16x16x32_f16(fa[m][0], fb[n][0], acc[m][n], 0, 0, 0);
                acc[m][n] = __builtin_amdgcn_mfma_f32_16x16x32_f16(fa[m][1], fb[n][1], acc[m][n], 0, 0, 0);
            }
    }

    const bool mirror = (bi != bj);
#pragma unroll
    for (int m = 0; m < 4; ++m)
#pragma unroll
        for (int n = 0; n < 4; ++n) {
            const int gj = col0 + wn + n * 16 + l15;
            const float invj = invn[gj];
#pragma unroll
            for (int r = 0; r < 4; ++r) {
                const int gi = row0 + wm + m * 16 + q * 4 + r;
                float v = acc[m][n][r] * invn[gi] * invj;
                if (gi == gj) v = -3.0e38f;
                Sm[(size_t)gi * MSAMP + gj] = v;
                if (mirror) Sm[(size_t)gj * MSAMP + gi] = v;
            }
        }
}

// ---------------------------------------------------------------------------
// Tk(f16) = tanh((1/k) * Adj @ Xe) via i8 MFMA. K-step 128 (2 x 64),
// bank-swizzled fragment LDS. XCD chunked swizzle (2048 = 8*256).
// ---------------------------------------------------------------------------
__global__ __launch_bounds__(256) void gemm_adj_i8(
    const unsigned* __restrict__ Abits, const signed char* __restrict__ XeT,
    unsigned short* __restrict__ Tk, const int* __restrict__ kp)
{
    __shared__ signed char BsF[8][2][64][16];    // 32 KiB
    __shared__ uint4 aw4[128];

    const int tid = threadIdx.x;
    const int wid = tid >> 6, lane = tid & 63;
    const int l15 = lane & 15, q = lane >> 4;
    const int wm = (wid >> 1) * 64, wn = (wid & 1) * 64;

    const int orig = blockIdx.x + blockIdx.y * 32;   // grid (32, 64), 2048 blocks
    const int s = (orig & 7) * 256 + (orig >> 3);    // bijective XCD chunking
    const int row0 = (s & 31) * 128;                 // sample rows
    const int col0 = (s >> 5) * 128;                 // expansion cols

    const int sr = tid >> 1;
    const int half = tid & 1;
    const int l_ws = (sr & 15) ^ (half << 2);
    const int lane_s = lane ^ ((lane >> 3) & 4);

    i32x4v acc[4][4];
#pragma unroll
    for (int m = 0; m < 4; ++m)
#pragma unroll
        for (int n = 0; n < 4; ++n) acc[m][n] = (i32x4v){0, 0, 0, 0};

    for (int k0 = 0; k0 < MSAMP; k0 += 128) {
        const signed char* pb = XeT + (size_t)(col0 + sr) * MSAMP + k0 + half * 32;
        i32x4v b0 = *(const i32x4v*)pb;
        i32x4v b1 = *(const i32x4v*)(pb + 16);
        i32x4v b2 = *(const i32x4v*)(pb + 64);
        i32x4v b3 = *(const i32x4v*)(pb + 80);
        uint4 wv = make_uint4(0u, 0u, 0u, 0u);
        if (tid < 128)
            wv = *(const uint4*)(Abits + (size_t)(row0 + tid) * (MSAMP / 32) + (k0 >> 5));

        __syncthreads();
        *(i32x4v*)&BsF[sr >> 4][0][(half * 2 + 0) * 16 + l_ws][0] = b0;
        *(i32x4v*)&BsF[sr >> 4][0][(half * 2 + 1) * 16 + l_ws][0] = b1;
        *(i32x4v*)&BsF[sr >> 4][1][(half * 2 + 0) * 16 + l_ws][0] = b2;
        *(i32x4v*)&BsF[sr >> 4][1][(half * 2 + 1) * 16 + l_ws][0] = b3;
        if (tid < 128) aw4[tid] = wv;
        __syncthreads();

        i32x4v fb[4][2];
#pragma unroll
        for (int n = 0; n < 4; ++n) {
            fb[n][0] = *(const i32x4v*)&BsF[(wn >> 4) + n][0][lane_s][0];
            fb[n][1] = *(const i32x4v*)&BsF[(wn >> 4) + n][1][lane_s][0];
        }

#pragma unroll
        for (int m = 0; m < 4; ++m) {
            const uint4 ww = aw4[wm + m * 16 + l15];
#pragma unroll
            for (int kh = 0; kh < 2; ++kh) {
                const unsigned w = (kh == 0) ? ((q >= 2) ? ww.y : ww.x)
                                             : ((q >= 2) ? ww.w : ww.z);
                const unsigned hw = (q & 1) ? (w >> 16) : w;
                i32x4v fa;
#pragma unroll
                for (int p = 0; p < 4; ++p)
                    fa[p] = (int)((((hw >> (4 * p)) & 0xFu) * 0x00204081u) & 0x01010101u);
#pragma unroll
                for (int n = 0; n < 4; ++n)
                    acc[m][n] = __builtin_amdgcn_mfma_i32_16x16x64_i8(fa, fb[n][kh], acc[m][n], 0, 0, 0);
            }
        }
    }

    const float kv = QSCALE / (float)(*kp);
#pragma unroll
    for (int m = 0; m < 4; ++m)
#pragma unroll
        for (int n = 0; n < 4; ++n) {
            const int gj = col0 + wn + n * 16 + l15;
#pragma unroll
            for (int r = 0; r < 4; ++r) {
                const int gi = row0 + wm + m * 16 + q * 4 + r;
                Tk[(size_t)gi * EXPN + gj] = f2h(tanh_fast((float)acc[m][n][r] * kv));
            }
        }
}

// ---------------------------------------------------------------------------
// W [8192][1000] f32 -> WT f16 [NPAD][8192], zero-padded rows.
// ---------------------------------------------------------------------------
__global__ void transpose_w(const float* __restrict__ src,
                            unsigned short* __restrict__ dst)
{
    __shared__ float t[32][33];
    const int k0 = blockIdx.x * 32, n0 = blockIdx.y * 32;
    const int tx = threadIdx.x, ty = threadIdx.y;
#pragma unroll
    for (int i = 0; i < 4; ++i) {
        const int n = n0 + tx;
        t[ty + 8 * i][tx] = (n < NCLS) ? src[(size_t)(k0 + ty + 8 * i) * NCLS + n] : 0.f;
    }
    __syncthreads();
#pragma unroll
    for (int i = 0; i < 4; ++i)
        dst[(size_t)(n0 + ty + 8 * i) * EXPN + k0 + tx] = f2h(t[tx][ty + 8 * i]);
}

// ---------------------------------------------------------------------------
// Split-K=4, NO atomics. XCD chunked swizzle on (x,y), z preserved.
// K-step 64 (2 x 32), bank-swizzled fragment LDS, relu at ds_write time (z<2).
// ---------------------------------------------------------------------------
__global__ __launch_bounds__(256) void gemm_out_split(
    const unsigned short* __restrict__ Xe, const unsigned short* __restrict__ Tk,
    const unsigned short* __restrict__ WmT, const unsigned short* __restrict__ WcT,
    float* __restrict__ Cout, unsigned short* __restrict__ Pf)
{
    __shared__ unsigned short AsF[8][2][64][8], BsF[8][2][64][8];   // 32 KiB

    const int tid = threadIdx.x;
    const int wid = tid >> 6, lane = tid & 63;
    const int l15 = lane & 15, q = lane >> 4;
    const int wm = (wid >> 1) * 64, wn = (wid & 1) * 64;

    const int orig = blockIdx.x + blockIdx.y * 8;    // 256 blocks per z
    const int s = (orig & 7) * 32 + (orig >> 3);     // bijective XCD chunking
    const int col0 = (s & 7) * 128;
    const int row0 = (s >> 3) * 128;
    const int zz = blockIdx.z;
    const bool xe_side = (zz < 2);
    const int kbase = (zz & 1) * (EXPN / 2);

    const unsigned short* Abase = xe_side ? Xe : Tk;
    const unsigned short* Bbase = xe_side ? WmT : WcT;

    const int sr = tid >> 1;
    const int scp = (tid & 1) * 2;
    const int mi_w = sr >> 4;
    const int l_ws = (sr & 15) ^ ((tid & 1) << 2);
    const int lane_s = lane ^ ((lane >> 3) & 4);

    f32x4 acc[4][4];
#pragma unroll
    for (int m = 0; m < 4; ++m)
#pragma unroll
        for (int n = 0; n < 4; ++n) acc[m][n] = (f32x4){0.f, 0.f, 0.f, 0.f};

    for (int kk = 0; kk < EXPN / 2; kk += 64) {
        const int k0 = kbase + kk;
        const unsigned short* pa = Abase + (size_t)(row0 + sr) * EXPN + k0 + scp * 8;
        const unsigned short* pb = Bbase + (size_t)(col0 + sr) * EXPN + k0 + scp * 8;
        ushort8v a0 = *(const ushort8v*)pa,        a1 = *(const ushort8v*)(pa + 8);
        ushort8v a2 = *(const ushort8v*)(pa + 32), a3 = *(const ushort8v*)(pa + 40);
        ushort8v b0 = *(const ushort8v*)pb,        b1 = *(const ushort8v*)(pb + 8);
        ushort8v b2 = *(const ushort8v*)(pb + 32), b3 = *(const ushort8v*)(pb + 40);
        if (xe_side) { a0 = relu8h(a0); a1 = relu8h(a1); a2 = relu8h(a2); a3 = relu8h(a3); }

        __syncthreads();
        *(ushort8v*)&AsF[mi_w][0][scp * 16 + l_ws][0]       = a0;
        *(ushort8v*)&AsF[mi_w][0][(scp + 1) * 16 + l_ws][0] = a1;
        *(ushort8v*)&AsF[mi_w][1][scp * 16 + l_ws][0]       = a2;
        *(ushort8v*)&AsF[mi_w][1][(scp + 1) * 16 + l_ws][0] = a3;
        *(ushort8v*)&BsF[mi_w][0][scp * 16 + l_ws][0]       = b0;
        *(ushort8v*)&BsF[mi_w][0][(scp + 1) * 16 + l_ws][0] = b1;
        *(ushort8v*)&BsF[mi_w][1][scp * 16 + l_ws][0]       = b2;
        *(ushort8v*)&BsF[mi_w][1][(scp + 1) * 16 + l_ws][0] = b3;
        __syncthreads();

        half8 fa[4][2], fb[4][2];
#pragma unroll
        for (int m = 0; m < 4; ++m) {
            fa[m][0] = as_half8(&AsF[(wm >> 4) + m][0][lane_s][0]);
            fa[m][1] = as_half8(&AsF[(wm >> 4) + m][1][lane_s][0]);
            fb[m][0] = as_half8(&BsF[(wn >> 4) + m][0][lane_s][0]);
            fb[m][1] = as_half8(&BsF[(wn >> 4) + m][1][lane_s][0]);
        }
#pragma unroll
        for (int m = 0; m < 4; ++m)
#pragma unroll
            for (int n = 0; n < 4; ++n) {
                acc[m][n] = __builtin_amdgcn_mfma_f32_16x16x32_f16(fa[m][0], fb[n][0], acc[m][n], 0, 0, 0);
                acc[m][n] = __builtin_amdgcn_mfma_f32_16x16x32_f16(fa[m][1], fb[n][1], acc[m][n], 0, 0, 0);
            }
    }

    if (zz == 0) {
#pragma unroll
        for (int m = 0; m < 4; ++m)
#pragma unroll
            for (int n = 0; n < 4; ++n) {
                const int gj = col0 + wn + n * 16 + l15;
                if (gj < NCLS) {
#pragma unroll
                    for (int r = 0; r < 4; ++r) {
                        const int gi = row0 + wm + m * 16 + q * 4 + r;
                        Cout[(size_t)gi * NCLS + gj] = acc[m][n][r];
                    }
                }
            }
    } else {
        unsigned short* dp = Pf + (size_t)(zz - 1) * MSAMP * NCLS;
#pragma unroll
        for (int m = 0; m < 4; ++m)
#pragma unroll
            for (int n = 0; n < 4; ++n) {
                const int gj = col0 + wn + n * 16 + l15;
                if (gj < NCLS) {
#pragma unroll
                    for (int r = 0; r < 4; ++r) {
                        const int gi = row0 + wm + m * 16 + q * 4 + r;
                        dp[(size_t)gi * NCLS + gj] = f2h(acc[m][n][r]);
                    }
                }
            }
    }
}

// ---------------------------------------------------------------------------
// out[i] += P0[i] + P1[i] + P2[i]   (f16 partials -> f32 accumulate)
// ---------------------------------------------------------------------------
__global__ __launch_bounds__(256) void add_partials(float* __restrict__ out,
                                                    const unsigned short* __restrict__ P,
                                                    int n4)
{
    const int i = blockIdx.x * 256 + threadIdx.x;
    if (i < n4) {
        float4 a = ((const float4*)out)[i];
        const ushort4 p0 = *(const ushort4*)(P + (size_t)i * 4);
        const ushort4 p1 = *(const ushort4*)(P + (size_t)MSAMP * NCLS + (size_t)i * 4);
        const ushort4 p2 = *(const ushort4*)(P + (size_t)2 * MSAMP * NCLS + (size_t)i * 4);
        a.x += h2f(p0.x) + h2f(p1.x) + h2f(p2.x);
        a.y += h2f(p0.y) + h2f(p1.y) + h2f(p2.y);
        a.z += h2f(p0.z) + h2f(p1.z) + h2f(p2.z);
        a.w += h2f(p0.w) + h2f(p1.w) + h2f(p2.w);
        ((float4*)out)[i] = a;
    }
}

// ---------------------------------------------------------------------------
__global__ __launch_bounds__(256) void row_invnorm(
    const unsigned short* __restrict__ Xe, float* __restrict__ invn)
{
    const int row = blockIdx.x;
    float s = 0.f;
    for (int j = threadIdx.x * 8; j < EXPN; j += 2048) {
        ushort8v h = *(const ushort8v*)(Xe + (size_t)row * EXPN + j);
#pragma unroll
        for (int c = 0; c < 8; ++c) { float x = h2f(h[c]); s += x * x; }
    }
#pragma unroll
    for (int off = 32; off > 0; off >>= 1) s += __shfl_down(s, off);
    __shared__ float wsum[4];
    if ((threadIdx.x & 63) == 0) wsum[threadIdx.x >> 6] = s;
    __syncthreads();
    if (threadIdx.x == 0)
        invn[row] = rsqrtf(wsum[0] + wsum[1] + wsum[2] + wsum[3]);
}

// ---------------------------------------------------------------------------
__global__ __launch_bounds__(256) void topk_thresh(const float* __restrict__ sim,
                                                   float* __restrict__ thr,
                                                   int N, const int* __restrict__ kp)
{
    const int row = blockIdx.x;
    const float* srow = sim + (size_t)row * N;
    __shared__ int hist[256];
    __shared__ unsigned s_prefix;
    __shared__ int s_rem;
    if (threadIdx.x == 0) { s_prefix = 0u; s_rem = *kp; }
    __syncthreads();

    for (int pass = 0; pass < 4; ++pass) {
        const int shift = 24 - 8 * pass;
        hist[threadIdx.x] = 0;
        __syncthreads();
        const unsigned prefix = s_prefix;
        const unsigned pmask = (pass == 0) ? 0u : (0xFFFFFFFFu << (shift + 8));
        for (int j = threadIdx.x; j < N; j += 256) {
            unsigned u = __float_as_uint(srow[j]);
            u = ((int)u < 0) ? ~u : (u | 0x80000000u);
            if ((u & pmask) == (prefix & pmask))
                atomicAdd(&hist[(u >> shift) & 255], 1);
        }
        __syncthreads();
        if (threadIdx.x == 0) {
            int rem = s_rem, accum = 0, b;
            for (b = 255; b > 0; --b) {
                if (accum + hist[b] >= rem) break;
                accum += hist[b];
            }
            s_rem = rem - accum;
            s_prefix = prefix | ((unsigned)b << shift);
        }
        __syncthreads();
    }

    if (threadIdx.x == 0) {
        const unsigned u = s_prefix;
        const unsigned orig = (u & 0x80000000u) ? (u & 0x7FFFFFFFu) : ~u;
        thr[row] = __uint_as_float(orig);
    }
}

// ---------------------------------------------------------------------------
__global__ __launch_bounds__(128) void bitpack(const float* __restrict__ Sm,
                                               const float* __restrict__ thr,
                                               unsigned* __restrict__ Abits)
{
    const int row = blockIdx.x;
    const int w = threadIdx.x;
    const float t = thr[row];
    const float* p = Sm + (size_t)row * MSAMP + w * 32;
    unsigned m = 0;
#pragma unroll
    for (int b = 0; b < 32; b += 4) {
        float4 v = *(const float4*)(p + b);
        m |= (v.x >= t ? 1u : 0u) << (b + 0);
        m |= (v.y >= t ? 1u : 0u) << (b + 1);
        m |= (v.z >= t ? 1u : 0u) << (b + 2);
        m |= (v.w >= t ? 1u : 0u) << (b + 3);
    }
    Abits[(size_t)row * (MSAMP / 32) + w] = m;
}

// ---------------------------------------------------------------------------
// XeT_i8[n][m] = clamp(round(Xe[m][n] * 127/6)) — transpose + quantize.
// ---------------------------------------------------------------------------
__global__ void transpose_xe_q(const unsigned short* __restrict__ src,
                               signed char* __restrict__ dst)
{
    __shared__ signed char t[32][36];
    const int bx = blockIdx.x;
    const int by = blockIdx.y;
    const int tx = threadIdx.x, ty = threadIdx.y;
#pragma unroll
    for (int i = 0; i < 4; ++i) {
        float v = h2f(src[(size_t)(by * 32 + ty + 8 * i) * EXPN + bx * 32 + tx]);
        int qv = (int)rintf(v * QSCALE_INV);
        qv = max(-127, min(127, qv));
        t[tx][ty + 8 * i] = (signed char)qv;
    }
    __syncthreads();
    const int tid = ty * 32 + tx;
    const int nl = tid >> 3, mg = (tid & 7) * 4;
    char4 o;
    o.x = t[nl][mg + 0]; o.y = t[nl][mg + 1];
    o.z = t[nl][mg + 2]; o.w = t[nl][mg + 3];
    *(char4*)&dst[(size_t)(bx * 32 + nl) * MSAMP + by * 32 + mg] = o;
}

// ---------------------------------------------------------------------------
extern "C" void kernel_launch(void* const* d_in, const int* in_sizes, int n_in,
                              void* d_out, int out_size, void* d_ws, size_t ws_size,
                              hipStream_t stream)
{
    const float* X  = (const float*)d_in[0];
    const float* Wb = (const float*)d_in[1];
    const float* Wm = (const float*)d_in[2];
    const float* Wc = (const float*)d_in[3];
    const int*   kp = (const int*)d_in[4];
    float* out = (float*)d_out;

    // Workspace (peak ~194 MiB, same envelope as prior rounds):
    //  SEG0 [0,64M)    Xe f16 [4096][8192]
    //  SEG1 [64,128M)  XeT_i8 (32M) -> WmT+WcT f16 (32M) | Pf f16 x3 @+32M (23.4M)
    //  SEG2 [128,192M) prep {Xh 4M, WbT 8M} -> Sm f32 -> Tk f16
    //  [192M..)        Abits (2 MiB), invn, thr
    char* base = (char*)d_ws;
    const size_t SEG = (size_t)64 << 20;
    const size_t need = 3 * SEG + ((size_t)2 << 20) + 65536;
    if (ws_size < need) return;

    unsigned short* Xe   = (unsigned short*)base;
    signed char*    XeTq = (signed char*)(base + SEG);
    unsigned short* WmT  = (unsigned short*)(base + SEG);        // overlay (after gemm_adj)
    unsigned short* WcT  = WmT + (size_t)NPAD * EXPN;            // +16 MiB
    unsigned short* Pf   = (unsigned short*)(base + SEG + ((size_t)32 << 20)); // 3 x 7.8 MiB
    unsigned short* Xh   = (unsigned short*)(base + 2 * SEG);               // 4 MB
    unsigned short* WbT  = Xh + (size_t)MSAMP * D0;                         // 8 MB
    float*          Sm   = (float*)(base + 2 * SEG);             // overlay (after gemm_xe)
    unsigned short* Tk   = (unsigned short*)(base + 2 * SEG);    // overlay (after bitpack)
    unsigned*       Abits= (unsigned*)(base + 3 * SEG);
    float*          invn = (float*)(base + 3 * SEG + ((size_t)2 << 20));
    float*          thr  = invn + MSAMP;

    const dim3 blk(256);

    // 0) prep: X -> f16, Wb -> WbT f16
    cvt_x<<<dim3((MSAMP * D0) / (256 * 8)), blk, 0, stream>>>(X, Xh);
    transpose_wb<<<dim3(EXPN / 32, D0 / 32), dim3(32, 8), 0, stream>>>(Wb, WbT);

    // 1) Xe = X @ Wb (f16 MFMA, K-step 64)
    gemm_xe_mfma<<<dim3(EXPN / 128, MSAMP / 128), blk, 0, stream>>>(Xh, WbT, Xe);

    // 2) row inverse norms
    row_invnorm<<<dim3(MSAMP), blk, 0, stream>>>(Xe, invn);

    // 3) sim (symmetric: 528 upper-tri blocks, mirrored writes, K-step 64)
    gemm_sim<<<dim3(528), blk, 0, stream>>>(Xe, invn, Sm);

    // 4) per-row k-th largest threshold (exact f32 radix select)
    topk_thresh<<<dim3(MSAMP), blk, 0, stream>>>(Sm, thr, MSAMP, kp);

    // 5) adjacency bitmask
    bitpack<<<dim3(MSAMP), dim3(128), 0, stream>>>(Sm, thr, Abits);

    // 6) XeT_i8 = quantized Xe^T (into SEG1)
    transpose_xe_q<<<dim3(EXPN / 32, MSAMP / 32), dim3(32, 8), 0, stream>>>(Xe, XeTq);

    // 7) Tk = tanh((1/k) Adj @ Xe) via i8 MFMA (K-step 128) — over dead Sm
    gemm_adj_i8<<<dim3(MSAMP / 128, EXPN / 128), blk, 0, stream>>>(Abits, XeTq, Tk, kp);

    // 8) W transposes (f16 NT) into dead XeT region
    transpose_w<<<dim3(EXPN / 32, NPAD / 32), dim3(32, 8), 0, stream>>>(Wm, WmT);
    transpose_w<<<dim3(EXPN / 32, NPAD / 32), dim3(32, 8), 0, stream>>>(Wc, WcT);

    // 9) split-K=4 output GEMM (K-step 64): z=0 -> f32 out, z=1..3 -> f16 partials
    gemm_out_split<<<dim3(NPAD / 128, MSAMP / 128, 4), blk, 0, stream>>>(
        Xe, Tk, WmT, WcT, out, Pf);

    // 10) out += P0+P1+P2 (kernel-boundary-ordered, XCD-safe)
    add_partials<<<dim3((MSAMP * NCLS / 4 + 255) / 256), blk, 0, stream>>>(
        out, Pf, MSAMP * NCLS / 4);
}